// Round 1
// baseline (1027.535 us; speedup 1.0000x reference)
//
#include <hip/hip_runtime.h>
#include <hip/hip_bf16.h>

// Problem constants (from reference)
#define NN 50000
#define NE 800000
#define ET (NE + NN)          // edges + self loops = 850000
#define FIN 256
#define HC 192                // H*C = 3*64
#define NHEAD 3
#define CDIM 64

// ---------------------------------------------------------------------------
// CSR build: histogram -> scan -> scatter (graph shared by all 3 GAT layers)
// ---------------------------------------------------------------------------
__global__ __launch_bounds__(256) void hist_kernel(const int* __restrict__ ei,
                                                   int* __restrict__ cnt) {
    int e = blockIdx.x * 256 + threadIdx.x;
    if (e >= ET) return;
    int dst = (e < NE) ? ei[NE + e] : (e - NE);
    atomicAdd(&cnt[dst], 1);
}

#define SCAN_BLK 1024
__global__ __launch_bounds__(SCAN_BLK) void scan1_kernel(const int* __restrict__ cnt,
                                                         int* __restrict__ row_ptr,
                                                         int* __restrict__ partials) {
    __shared__ int sm[SCAN_BLK];
    int t = threadIdx.x;
    int g = blockIdx.x * SCAN_BLK + t;
    int v = (g < NN) ? cnt[g] : 0;
    sm[t] = v;
    __syncthreads();
    for (int off = 1; off < SCAN_BLK; off <<= 1) {
        int u = (t >= off) ? sm[t - off] : 0;
        __syncthreads();
        sm[t] += u;
        __syncthreads();
    }
    if (g < NN) row_ptr[g + 1] = sm[t];           // inclusive within chunk
    if (t == SCAN_BLK - 1) partials[blockIdx.x] = sm[t];
}

__global__ __launch_bounds__(64) void scan2_kernel(int* __restrict__ partials, int nb) {
    int t = threadIdx.x;                           // single 64-lane wave
    int v = (t < nb) ? partials[t] : 0;
    int x = v;
    for (int off = 1; off < 64; off <<= 1) {
        int y = __shfl_up(x, off);
        if (t >= off) x += y;
    }
    if (t < nb) partials[t] = x - v;               // exclusive
}

__global__ __launch_bounds__(SCAN_BLK) void scan3_kernel(int* __restrict__ row_ptr,
                                                         const int* __restrict__ partials) {
    int g = blockIdx.x * SCAN_BLK + threadIdx.x;
    if (g < NN) row_ptr[g + 1] += partials[blockIdx.x];
    if (g == 0) row_ptr[0] = 0;
}

__global__ __launch_bounds__(256) void scatter_kernel(const int* __restrict__ ei,
                                                      int* __restrict__ cnt,
                                                      const int* __restrict__ row_ptr,
                                                      int* __restrict__ csr_src) {
    int e = blockIdx.x * 256 + threadIdx.x;
    if (e >= ET) return;
    int src, dst;
    if (e < NE) { src = ei[e]; dst = ei[NE + e]; }
    else        { src = e - NE; dst = e - NE; }
    int pos = atomicAdd(&cnt[dst], 1);
    csr_src[row_ptr[dst] + pos] = src;
}

// ---------------------------------------------------------------------------
// SGEMM: C[M,N] = A[M,K] * B[N,K]^T   (both row-major, K-contiguous)
// BM=BN=BK=64, 256 threads, 4x4 micro-tile, k-major LDS (2x ds_read_b128/k)
// Requires K%64==0, N%64==0.
// ---------------------------------------------------------------------------
__global__ __launch_bounds__(256) void sgemm_nt(const float* __restrict__ A,
                                                const float* __restrict__ B,
                                                float* __restrict__ C,
                                                int M, int N, int K) {
    __shared__ float As[64][68];   // [k][m], +4 pad keeps 16B alignment
    __shared__ float Bs[64][68];   // [k][n]
    const int tid = threadIdx.x;
    const int tx = tid & 15;       // col group
    const int ty = tid >> 4;       // row group
    const int m0 = blockIdx.x * 64;
    const int n0 = blockIdx.y * 64;
    const int lrow = tid >> 4;     // 0..15
    const int lk = (tid & 15) * 4; // 0..60

    float acc[4][4];
#pragma unroll
    for (int i = 0; i < 4; i++)
#pragma unroll
        for (int j = 0; j < 4; j++) acc[i][j] = 0.f;

    for (int k0 = 0; k0 < K; k0 += 64) {
#pragma unroll
        for (int i = 0; i < 4; i++) {
            int r = lrow + i * 16;
            int gm = m0 + r;
            float4 v = make_float4(0.f, 0.f, 0.f, 0.f);
            if (gm < M) v = *reinterpret_cast<const float4*>(&A[(size_t)gm * K + k0 + lk]);
            As[lk + 0][r] = v.x; As[lk + 1][r] = v.y;
            As[lk + 2][r] = v.z; As[lk + 3][r] = v.w;
        }
#pragma unroll
        for (int i = 0; i < 4; i++) {
            int r = lrow + i * 16;
            float4 v = *reinterpret_cast<const float4*>(&B[(size_t)(n0 + r) * K + k0 + lk]);
            Bs[lk + 0][r] = v.x; Bs[lk + 1][r] = v.y;
            Bs[lk + 2][r] = v.z; Bs[lk + 3][r] = v.w;
        }
        __syncthreads();
#pragma unroll 8
        for (int k = 0; k < 64; k++) {
            const float4 av = *reinterpret_cast<const float4*>(&As[k][ty * 4]);
            const float4 bv = *reinterpret_cast<const float4*>(&Bs[k][tx * 4]);
            const float a[4] = {av.x, av.y, av.z, av.w};
            const float b[4] = {bv.x, bv.y, bv.z, bv.w};
#pragma unroll
            for (int i = 0; i < 4; i++)
#pragma unroll
                for (int j = 0; j < 4; j++) acc[i][j] = fmaf(a[i], b[j], acc[i][j]);
        }
        __syncthreads();
    }
#pragma unroll
    for (int i = 0; i < 4; i++) {
        int gm = m0 + ty * 4 + i;
        if (gm < M) {
            float4 v = make_float4(acc[i][0], acc[i][1], acc[i][2], acc[i][3]);
            *reinterpret_cast<float4*>(&C[(size_t)gm * N + n0 + tx * 4]) = v;
        }
    }
}

// ---------------------------------------------------------------------------
// Attention logits: al_src[n,h] = sum_c h[n,h,c]*a_src[h,c]; same for dst.
// One wave per (node, head).
// ---------------------------------------------------------------------------
__global__ __launch_bounds__(256) void al_kernel(const float* __restrict__ h,
                                                 const float* __restrict__ a_src,
                                                 const float* __restrict__ a_dst,
                                                 float* __restrict__ al_src,
                                                 float* __restrict__ al_dst) {
    int wid = (blockIdx.x * 256 + threadIdx.x) >> 6;
    int lane = threadIdx.x & 63;
    if (wid >= NN * NHEAD) return;
    int n = wid / 3;
    int head = wid - n * 3;
    float v = h[(size_t)n * HC + head * CDIM + lane];
    float ps = v * a_src[head * CDIM + lane];
    float pd = v * a_dst[head * CDIM + lane];
#pragma unroll
    for (int off = 32; off; off >>= 1) {
        ps += __shfl_xor(ps, off);
        pd += __shfl_xor(pd, off);
    }
    if (lane == 0) { al_src[wid] = ps; al_dst[wid] = pd; }
}

// ---------------------------------------------------------------------------
// Layer-1 aggregation: per node, 3 waves (one/head), lane=channel.
// Softmax over incoming edges + weighted sum, then +bias, relu (concat).
// ---------------------------------------------------------------------------
__global__ __launch_bounds__(192) void agg_cat_kernel(const int* __restrict__ row_ptr,
                                                      const int* __restrict__ csr_src,
                                                      const float* __restrict__ h,
                                                      const float* __restrict__ al_src,
                                                      const float* __restrict__ al_dst,
                                                      const float* __restrict__ bias,
                                                      float* __restrict__ out) {
    int n = blockIdx.x;
    int head = threadIdx.x >> 6;
    int lane = threadIdx.x & 63;
    int start = row_ptr[n], end = row_ptr[n + 1];
    float ad = al_dst[n * 3 + head];

    float m = -1e30f;
    for (int j = start + lane; j < end; j += 64) {
        float a = al_src[csr_src[j] * 3 + head] + ad;
        a = a > 0.f ? a : 0.2f * a;
        m = fmaxf(m, a);
    }
#pragma unroll
    for (int off = 32; off; off >>= 1) m = fmaxf(m, __shfl_xor(m, off));

    float acc = 0.f, ssum = 0.f;
    for (int j = start; j < end; ++j) {
        int s = csr_src[j];
        float a = al_src[s * 3 + head] + ad;
        a = a > 0.f ? a : 0.2f * a;
        float w = __expf(a - m);
        ssum += w;
        acc += w * h[(size_t)s * HC + head * CDIM + lane];
    }
    float o = acc / (ssum + 1e-16f) + bias[head * CDIM + lane];
    out[(size_t)n * HC + head * CDIM + lane] = fmaxf(o, 0.f);
}

// ---------------------------------------------------------------------------
// mu/lv aggregation fused: 6 waves/node (3 mu heads + 3 lv heads),
// mean over heads + bias, write straight into d_out (mu then logvar).
// ---------------------------------------------------------------------------
__global__ __launch_bounds__(384) void agg_mean2_kernel(const int* __restrict__ row_ptr,
                                                        const int* __restrict__ csr_src,
                                                        const float* __restrict__ h_mu,
                                                        const float* __restrict__ h_lv,
                                                        const float* __restrict__ alms,
                                                        const float* __restrict__ almd,
                                                        const float* __restrict__ alls,
                                                        const float* __restrict__ alld,
                                                        const float* __restrict__ b_mu,
                                                        const float* __restrict__ b_lv,
                                                        float* __restrict__ out) {
    __shared__ float red[6][64];
    int n = blockIdx.x;
    int hh = threadIdx.x >> 6;     // 0..5
    int lane = threadIdx.x & 63;
    int head = (hh < 3) ? hh : hh - 3;
    const float* h  = (hh < 3) ? h_mu : h_lv;
    const float* as = (hh < 3) ? alms : alls;
    const float* ap = (hh < 3) ? almd : alld;
    int start = row_ptr[n], end = row_ptr[n + 1];
    float ad = ap[n * 3 + head];

    float m = -1e30f;
    for (int j = start + lane; j < end; j += 64) {
        float a = as[csr_src[j] * 3 + head] + ad;
        a = a > 0.f ? a : 0.2f * a;
        m = fmaxf(m, a);
    }
#pragma unroll
    for (int off = 32; off; off >>= 1) m = fmaxf(m, __shfl_xor(m, off));

    float acc = 0.f, ssum = 0.f;
    for (int j = start; j < end; ++j) {
        int s = csr_src[j];
        float a = as[s * 3 + head] + ad;
        a = a > 0.f ? a : 0.2f * a;
        float w = __expf(a - m);
        ssum += w;
        acc += w * h[(size_t)s * HC + head * CDIM + lane];
    }
    red[hh][lane] = acc / (ssum + 1e-16f);
    __syncthreads();
    if (threadIdx.x < 64) {
        out[(size_t)n * CDIM + lane] =
            (red[0][lane] + red[1][lane] + red[2][lane]) * (1.f / 3.f) + b_mu[lane];
    } else if (threadIdx.x < 128) {
        out[(size_t)NN * CDIM + (size_t)n * CDIM + lane] =
            (red[3][lane] + red[4][lane] + red[5][lane]) * (1.f / 3.f) + b_lv[lane];
    }
}

// ---------------------------------------------------------------------------
extern "C" void kernel_launch(void* const* d_in, const int* in_sizes, int n_in,
                              void* d_out, int out_size, void* d_ws, size_t ws_size,
                              hipStream_t stream) {
    const float* x    = (const float*)d_in[0];
    const int*   ei   = (const int*)d_in[1];
    const float* W1   = (const float*)d_in[2];
    const float* a1s  = (const float*)d_in[3];
    const float* a1d  = (const float*)d_in[4];
    const float* b1   = (const float*)d_in[5];
    const float* Wmu  = (const float*)d_in[6];
    const float* amus = (const float*)d_in[7];
    const float* amud = (const float*)d_in[8];
    const float* bmu  = (const float*)d_in[9];
    const float* Wlv  = (const float*)d_in[10];
    const float* alvs = (const float*)d_in[11];
    const float* alvd = (const float*)d_in[12];
    const float* blv  = (const float*)d_in[13];
    float* out = (float*)d_out;

    // workspace carve (256B aligned)
    size_t off = 0;
    auto carve = [&](size_t bytes) {
        void* p = (char*)d_ws + off;
        off += (bytes + 255) & ~(size_t)255;
        return p;
    };
    int*   cnt      = (int*)carve((size_t)NN * 4);
    int*   row_ptr  = (int*)carve((size_t)(NN + 1) * 4);
    int*   partials = (int*)carve(64 * 4);
    int*   csr      = (int*)carve((size_t)ET * 4);
    float* h1       = (float*)carve((size_t)NN * HC * 4);   // reused as h_mu
    float* hrelu    = (float*)carve((size_t)NN * HC * 4);
    float* h_lv     = (float*)carve((size_t)NN * HC * 4);
    float* al1s     = (float*)carve((size_t)NN * 3 * 4);
    float* al1d     = (float*)carve((size_t)NN * 3 * 4);
    float* alms     = (float*)carve((size_t)NN * 3 * 4);
    float* almd     = (float*)carve((size_t)NN * 3 * 4);
    float* alls     = (float*)carve((size_t)NN * 3 * 4);
    float* alld     = (float*)carve((size_t)NN * 3 * 4);
    float* h_mu = h1;

    const int scan_blocks = (NN + SCAN_BLK - 1) / SCAN_BLK;  // 49

    // ---- CSR build (shared by all 3 layers) ----
    hipMemsetAsync(cnt, 0, (size_t)NN * 4, stream);
    hist_kernel<<<(ET + 255) / 256, 256, 0, stream>>>(ei, cnt);
    scan1_kernel<<<scan_blocks, SCAN_BLK, 0, stream>>>(cnt, row_ptr, partials);
    scan2_kernel<<<1, 64, 0, stream>>>(partials, scan_blocks);
    scan3_kernel<<<scan_blocks, SCAN_BLK, 0, stream>>>(row_ptr, partials);
    hipMemsetAsync(cnt, 0, (size_t)NN * 4, stream);
    scatter_kernel<<<(ET + 255) / 256, 256, 0, stream>>>(ei, cnt, row_ptr, csr);

    // ---- Layer 1 ----
    dim3 g1((NN + 63) / 64, HC / 64);
    sgemm_nt<<<g1, 256, 0, stream>>>(x, W1, h1, NN, HC, FIN);
    al_kernel<<<(NN * 3 + 3) / 4, 256, 0, stream>>>(h1, a1s, a1d, al1s, al1d);
    agg_cat_kernel<<<NN, 192, 0, stream>>>(row_ptr, csr, h1, al1s, al1d, b1, hrelu);

    // ---- Layers mu / lv ----
    sgemm_nt<<<g1, 256, 0, stream>>>(hrelu, Wmu, h_mu, NN, HC, HC);
    sgemm_nt<<<g1, 256, 0, stream>>>(hrelu, Wlv, h_lv, NN, HC, HC);
    al_kernel<<<(NN * 3 + 3) / 4, 256, 0, stream>>>(h_mu, amus, amud, alms, almd);
    al_kernel<<<(NN * 3 + 3) / 4, 256, 0, stream>>>(h_lv, alvs, alvd, alls, alld);
    agg_mean2_kernel<<<NN, 384, 0, stream>>>(row_ptr, csr, h_mu, h_lv,
                                             alms, almd, alls, alld, bmu, blv, out);
}

// Round 2
// 787.775 us; speedup vs baseline: 1.3044x; 1.3044x over previous
//
#include <hip/hip_runtime.h>
#include <hip/hip_bf16.h>

// Problem constants (from reference)
#define NN 50000
#define NE 800000
#define ET (NE + NN)          // edges + self loops = 850000
#define FIN 256
#define HC 192                // H*C = 3*64
#define NHEAD 3
#define CDIM 64
#define MAXDEG 128            // fast-path cap; Poisson(16) max over 50K nodes ~45

// ---------------------------------------------------------------------------
// CSR build: histogram -> scan -> scatter (graph shared by all 3 GAT layers)
// ---------------------------------------------------------------------------
__global__ __launch_bounds__(256) void hist_kernel(const int* __restrict__ ei,
                                                   int* __restrict__ cnt) {
    int e = blockIdx.x * 256 + threadIdx.x;
    if (e >= ET) return;
    int dst = (e < NE) ? ei[NE + e] : (e - NE);
    atomicAdd(&cnt[dst], 1);
}

#define SCAN_BLK 1024
__global__ __launch_bounds__(SCAN_BLK) void scan1_kernel(const int* __restrict__ cnt,
                                                         int* __restrict__ row_ptr,
                                                         int* __restrict__ partials) {
    __shared__ int sm[SCAN_BLK];
    int t = threadIdx.x;
    int g = blockIdx.x * SCAN_BLK + t;
    int v = (g < NN) ? cnt[g] : 0;
    sm[t] = v;
    __syncthreads();
    for (int off = 1; off < SCAN_BLK; off <<= 1) {
        int u = (t >= off) ? sm[t - off] : 0;
        __syncthreads();
        sm[t] += u;
        __syncthreads();
    }
    if (g < NN) row_ptr[g + 1] = sm[t];           // inclusive within chunk
    if (t == SCAN_BLK - 1) partials[blockIdx.x] = sm[t];
}

__global__ __launch_bounds__(64) void scan2_kernel(int* __restrict__ partials, int nb) {
    int t = threadIdx.x;                           // single 64-lane wave
    int v = (t < nb) ? partials[t] : 0;
    int x = v;
    for (int off = 1; off < 64; off <<= 1) {
        int y = __shfl_up(x, off);
        if (t >= off) x += y;
    }
    if (t < nb) partials[t] = x - v;               // exclusive
}

__global__ __launch_bounds__(SCAN_BLK) void scan3_kernel(int* __restrict__ row_ptr,
                                                         const int* __restrict__ partials) {
    int g = blockIdx.x * SCAN_BLK + threadIdx.x;
    if (g < NN) row_ptr[g + 1] += partials[blockIdx.x];
    if (g == 0) row_ptr[0] = 0;
}

__global__ __launch_bounds__(256) void scatter_kernel(const int* __restrict__ ei,
                                                      int* __restrict__ cnt,
                                                      const int* __restrict__ row_ptr,
                                                      int* __restrict__ csr_src) {
    int e = blockIdx.x * 256 + threadIdx.x;
    if (e >= ET) return;
    int src, dst;
    if (e < NE) { src = ei[e]; dst = ei[NE + e]; }
    else        { src = e - NE; dst = e - NE; }
    int pos = atomicAdd(&cnt[dst], 1);
    csr_src[row_ptr[dst] + pos] = src;
}

// ---------------------------------------------------------------------------
// SGEMM: C[M,N] = A[M,K] * B[N,K]^T   (both row-major, K-contiguous)
// BM=BN=BK=64, 256 threads, 4x4 micro-tile, k-major LDS
// ---------------------------------------------------------------------------
__global__ __launch_bounds__(256) void sgemm_nt(const float* __restrict__ A,
                                                const float* __restrict__ B,
                                                float* __restrict__ C,
                                                int M, int N, int K) {
    __shared__ float As[64][68];
    __shared__ float Bs[64][68];
    const int tid = threadIdx.x;
    const int tx = tid & 15;
    const int ty = tid >> 4;
    const int m0 = blockIdx.x * 64;
    const int n0 = blockIdx.y * 64;
    const int lrow = tid >> 4;
    const int lk = (tid & 15) * 4;

    float acc[4][4];
#pragma unroll
    for (int i = 0; i < 4; i++)
#pragma unroll
        for (int j = 0; j < 4; j++) acc[i][j] = 0.f;

    for (int k0 = 0; k0 < K; k0 += 64) {
#pragma unroll
        for (int i = 0; i < 4; i++) {
            int r = lrow + i * 16;
            int gm = m0 + r;
            float4 v = make_float4(0.f, 0.f, 0.f, 0.f);
            if (gm < M) v = *reinterpret_cast<const float4*>(&A[(size_t)gm * K + k0 + lk]);
            As[lk + 0][r] = v.x; As[lk + 1][r] = v.y;
            As[lk + 2][r] = v.z; As[lk + 3][r] = v.w;
        }
#pragma unroll
        for (int i = 0; i < 4; i++) {
            int r = lrow + i * 16;
            float4 v = *reinterpret_cast<const float4*>(&B[(size_t)(n0 + r) * K + k0 + lk]);
            Bs[lk + 0][r] = v.x; Bs[lk + 1][r] = v.y;
            Bs[lk + 2][r] = v.z; Bs[lk + 3][r] = v.w;
        }
        __syncthreads();
#pragma unroll 8
        for (int k = 0; k < 64; k++) {
            const float4 av = *reinterpret_cast<const float4*>(&As[k][ty * 4]);
            const float4 bv = *reinterpret_cast<const float4*>(&Bs[k][tx * 4]);
            const float a[4] = {av.x, av.y, av.z, av.w};
            const float b[4] = {bv.x, bv.y, bv.z, bv.w};
#pragma unroll
            for (int i = 0; i < 4; i++)
#pragma unroll
                for (int j = 0; j < 4; j++) acc[i][j] = fmaf(a[i], b[j], acc[i][j]);
        }
        __syncthreads();
    }
#pragma unroll
    for (int i = 0; i < 4; i++) {
        int gm = m0 + ty * 4 + i;
        if (gm < M) {
            float4 v = make_float4(acc[i][0], acc[i][1], acc[i][2], acc[i][3]);
            *reinterpret_cast<float4*>(&C[(size_t)gm * N + n0 + tx * 4]) = v;
        }
    }
}

// ---------------------------------------------------------------------------
// Attention logits: al_src[n,h] = sum_c h[n,h,c]*a_src[h,c]; same for dst.
// ---------------------------------------------------------------------------
__global__ __launch_bounds__(256) void al_kernel(const float* __restrict__ h,
                                                 const float* __restrict__ a_src,
                                                 const float* __restrict__ a_dst,
                                                 float* __restrict__ al_src,
                                                 float* __restrict__ al_dst) {
    int wid = (blockIdx.x * 256 + threadIdx.x) >> 6;
    int lane = threadIdx.x & 63;
    if (wid >= NN * NHEAD) return;
    int n = wid / 3;
    int head = wid - n * 3;
    float v = h[(size_t)n * HC + head * CDIM + lane];
    float ps = v * a_src[head * CDIM + lane];
    float pd = v * a_dst[head * CDIM + lane];
#pragma unroll
    for (int off = 32; off; off >>= 1) {
        ps += __shfl_xor(ps, off);
        pd += __shfl_xor(pd, off);
    }
    if (lane == 0) { al_src[wid] = ps; al_dst[wid] = pd; }
}

// ---------------------------------------------------------------------------
// Per-wave softmax-weight computation into LDS (shared by both agg kernels).
// Edge list already staged in slds[0..deg). Each wave owns wrow[0..deg).
// Returns the softmax denominator (sum of exp), wrow[j] = exp(logit_j - max).
// ---------------------------------------------------------------------------
__device__ __forceinline__ float edge_weights(const int* slds, float* wrow,
                                              const float* __restrict__ al_s,
                                              float ad, int head, int deg, int lane) {
    float m = -1e30f;
    for (int j = lane; j < deg; j += 64) {
        float a = al_s[slds[j] * 3 + head] + ad;
        a = a > 0.f ? a : 0.2f * a;
        wrow[j] = a;
        m = fmaxf(m, a);
    }
#pragma unroll
    for (int off = 32; off; off >>= 1) m = fmaxf(m, __shfl_xor(m, off));
    float ssum = 0.f;
    for (int j = lane; j < deg; j += 64) {
        float w = __expf(wrow[j] - m);
        wrow[j] = w;
        ssum += w;
    }
#pragma unroll
    for (int off = 32; off; off >>= 1) ssum += __shfl_xor(ssum, off);
    return ssum;
}

// Weighted gather-accumulate, 4-way unrolled for memory-level parallelism.
__device__ __forceinline__ float gather_acc(const int* slds, const float* wrow,
                                            const float* __restrict__ h,
                                            int head, int deg, int lane) {
    float acc = 0.f;
    int j = 0;
    for (; j + 4 <= deg; j += 4) {
        int s0 = slds[j], s1 = slds[j + 1], s2 = slds[j + 2], s3 = slds[j + 3];
        float w0 = wrow[j], w1 = wrow[j + 1], w2 = wrow[j + 2], w3 = wrow[j + 3];
        float h0 = h[(size_t)s0 * HC + head * CDIM + lane];
        float h1 = h[(size_t)s1 * HC + head * CDIM + lane];
        float h2 = h[(size_t)s2 * HC + head * CDIM + lane];
        float h3 = h[(size_t)s3 * HC + head * CDIM + lane];
        acc = fmaf(w0, h0, acc);
        acc = fmaf(w1, h1, acc);
        acc = fmaf(w2, h2, acc);
        acc = fmaf(w3, h3, acc);
    }
    for (; j < deg; ++j)
        acc = fmaf(wrow[j], h[(size_t)slds[j] * HC + head * CDIM + lane], acc);
    return acc;
}

// ---------------------------------------------------------------------------
// Layer-1 aggregation (concat + bias + relu). 3 waves/node, lane = channel.
// ---------------------------------------------------------------------------
__global__ __launch_bounds__(192) void agg_cat_kernel(const int* __restrict__ row_ptr,
                                                      const int* __restrict__ csr_src,
                                                      const float* __restrict__ h,
                                                      const float* __restrict__ al_src,
                                                      const float* __restrict__ al_dst,
                                                      const float* __restrict__ bias,
                                                      float* __restrict__ out) {
    __shared__ int slds[MAXDEG];
    __shared__ float wlds[3][MAXDEG];
    int n = blockIdx.x;
    int head = threadIdx.x >> 6;
    int lane = threadIdx.x & 63;
    int start = row_ptr[n];
    int deg = row_ptr[n + 1] - start;
    float ad = al_dst[n * 3 + head];
    float acc, ssum;

    if (deg <= MAXDEG) {
        if (threadIdx.x < deg) slds[threadIdx.x] = csr_src[start + threadIdx.x];
        __syncthreads();
        ssum = edge_weights(slds, wlds[head], al_src, ad, head, deg, lane);
        acc = gather_acc(slds, wlds[head], h, head, deg, lane);
    } else {  // streaming fallback (never hit for this graph; correctness-safe)
        float m = -1e30f;
        for (int j = start + lane; j < start + deg; j += 64) {
            float a = al_src[csr_src[j] * 3 + head] + ad;
            a = a > 0.f ? a : 0.2f * a;
            m = fmaxf(m, a);
        }
#pragma unroll
        for (int off = 32; off; off >>= 1) m = fmaxf(m, __shfl_xor(m, off));
        acc = 0.f; ssum = 0.f;
        for (int j = start; j < start + deg; ++j) {
            int s = csr_src[j];
            float a = al_src[s * 3 + head] + ad;
            a = a > 0.f ? a : 0.2f * a;
            float w = __expf(a - m);
            ssum += w;
            acc = fmaf(w, h[(size_t)s * HC + head * CDIM + lane], acc);
        }
    }
    float o = acc / (ssum + 1e-16f) + bias[head * CDIM + lane];
    out[(size_t)n * HC + head * CDIM + lane] = fmaxf(o, 0.f);
}

// ---------------------------------------------------------------------------
// mu/lv aggregation fused: 6 waves/node (3 mu + 3 lv heads), mean over heads.
// ---------------------------------------------------------------------------
__global__ __launch_bounds__(384) void agg_mean2_kernel(const int* __restrict__ row_ptr,
                                                        const int* __restrict__ csr_src,
                                                        const float* __restrict__ h_mu,
                                                        const float* __restrict__ h_lv,
                                                        const float* __restrict__ alms,
                                                        const float* __restrict__ almd,
                                                        const float* __restrict__ alls,
                                                        const float* __restrict__ alld,
                                                        const float* __restrict__ b_mu,
                                                        const float* __restrict__ b_lv,
                                                        float* __restrict__ out) {
    __shared__ int slds[MAXDEG];
    __shared__ float wlds[6][MAXDEG];
    __shared__ float red[6][64];
    int n = blockIdx.x;
    int hh = threadIdx.x >> 6;     // 0..5
    int lane = threadIdx.x & 63;
    int head = (hh < 3) ? hh : hh - 3;
    const float* h  = (hh < 3) ? h_mu : h_lv;
    const float* as = (hh < 3) ? alms : alls;
    const float* ap = (hh < 3) ? almd : alld;
    int start = row_ptr[n];
    int deg = row_ptr[n + 1] - start;
    float ad = ap[n * 3 + head];
    float acc, ssum;

    if (deg <= MAXDEG) {
        if (threadIdx.x < deg) slds[threadIdx.x] = csr_src[start + threadIdx.x];
        __syncthreads();
        ssum = edge_weights(slds, wlds[hh], as, ad, head, deg, lane);
        acc = gather_acc(slds, wlds[hh], h, head, deg, lane);
    } else {  // streaming fallback
        float m = -1e30f;
        for (int j = start + lane; j < start + deg; j += 64) {
            float a = as[csr_src[j] * 3 + head] + ad;
            a = a > 0.f ? a : 0.2f * a;
            m = fmaxf(m, a);
        }
#pragma unroll
        for (int off = 32; off; off >>= 1) m = fmaxf(m, __shfl_xor(m, off));
        acc = 0.f; ssum = 0.f;
        for (int j = start; j < start + deg; ++j) {
            int s = csr_src[j];
            float a = as[s * 3 + head] + ad;
            a = a > 0.f ? a : 0.2f * a;
            float w = __expf(a - m);
            ssum += w;
            acc = fmaf(w, h[(size_t)s * HC + head * CDIM + lane], acc);
        }
    }
    red[hh][lane] = acc / (ssum + 1e-16f);
    __syncthreads();
    if (threadIdx.x < 64) {
        out[(size_t)n * CDIM + lane] =
            (red[0][lane] + red[1][lane] + red[2][lane]) * (1.f / 3.f) + b_mu[lane];
    } else if (threadIdx.x < 128) {
        out[(size_t)NN * CDIM + (size_t)n * CDIM + lane] =
            (red[3][lane] + red[4][lane] + red[5][lane]) * (1.f / 3.f) + b_lv[lane];
    }
}

// ---------------------------------------------------------------------------
extern "C" void kernel_launch(void* const* d_in, const int* in_sizes, int n_in,
                              void* d_out, int out_size, void* d_ws, size_t ws_size,
                              hipStream_t stream) {
    const float* x    = (const float*)d_in[0];
    const int*   ei   = (const int*)d_in[1];
    const float* W1   = (const float*)d_in[2];
    const float* a1s  = (const float*)d_in[3];
    const float* a1d  = (const float*)d_in[4];
    const float* b1   = (const float*)d_in[5];
    const float* Wmu  = (const float*)d_in[6];
    const float* amus = (const float*)d_in[7];
    const float* amud = (const float*)d_in[8];
    const float* bmu  = (const float*)d_in[9];
    const float* Wlv  = (const float*)d_in[10];
    const float* alvs = (const float*)d_in[11];
    const float* alvd = (const float*)d_in[12];
    const float* blv  = (const float*)d_in[13];
    float* out = (float*)d_out;

    // workspace carve (256B aligned)
    size_t off = 0;
    auto carve = [&](size_t bytes) {
        void* p = (char*)d_ws + off;
        off += (bytes + 255) & ~(size_t)255;
        return p;
    };
    int*   cnt      = (int*)carve((size_t)NN * 4);
    int*   row_ptr  = (int*)carve((size_t)(NN + 1) * 4);
    int*   partials = (int*)carve(64 * 4);
    int*   csr      = (int*)carve((size_t)ET * 4);
    float* h1       = (float*)carve((size_t)NN * HC * 4);   // reused as h_mu
    float* hrelu    = (float*)carve((size_t)NN * HC * 4);
    float* h_lv     = (float*)carve((size_t)NN * HC * 4);
    float* al1s     = (float*)carve((size_t)NN * 3 * 4);
    float* al1d     = (float*)carve((size_t)NN * 3 * 4);
    float* alms     = (float*)carve((size_t)NN * 3 * 4);
    float* almd     = (float*)carve((size_t)NN * 3 * 4);
    float* alls     = (float*)carve((size_t)NN * 3 * 4);
    float* alld     = (float*)carve((size_t)NN * 3 * 4);
    float* h_mu = h1;

    const int scan_blocks = (NN + SCAN_BLK - 1) / SCAN_BLK;  // 49

    // ---- CSR build (shared by all 3 layers) ----
    hipMemsetAsync(cnt, 0, (size_t)NN * 4, stream);
    hist_kernel<<<(ET + 255) / 256, 256, 0, stream>>>(ei, cnt);
    scan1_kernel<<<scan_blocks, SCAN_BLK, 0, stream>>>(cnt, row_ptr, partials);
    scan2_kernel<<<1, 64, 0, stream>>>(partials, scan_blocks);
    scan3_kernel<<<scan_blocks, SCAN_BLK, 0, stream>>>(row_ptr, partials);
    hipMemsetAsync(cnt, 0, (size_t)NN * 4, stream);
    scatter_kernel<<<(ET + 255) / 256, 256, 0, stream>>>(ei, cnt, row_ptr, csr);

    // ---- Layer 1 ----
    dim3 g1((NN + 63) / 64, HC / 64);
    sgemm_nt<<<g1, 256, 0, stream>>>(x, W1, h1, NN, HC, FIN);
    al_kernel<<<(NN * 3 + 3) / 4, 256, 0, stream>>>(h1, a1s, a1d, al1s, al1d);
    agg_cat_kernel<<<NN, 192, 0, stream>>>(row_ptr, csr, h1, al1s, al1d, b1, hrelu);

    // ---- Layers mu / lv ----
    sgemm_nt<<<g1, 256, 0, stream>>>(hrelu, Wmu, h_mu, NN, HC, HC);
    sgemm_nt<<<g1, 256, 0, stream>>>(hrelu, Wlv, h_lv, NN, HC, HC);
    al_kernel<<<(NN * 3 + 3) / 4, 256, 0, stream>>>(h_mu, amus, amud, alms, almd);
    al_kernel<<<(NN * 3 + 3) / 4, 256, 0, stream>>>(h_lv, alvs, alvd, alls, alld);
    agg_mean2_kernel<<<NN, 384, 0, stream>>>(row_ptr, csr, h_mu, h_lv,
                                             alms, almd, alls, alld, bmu, blv, out);
}

// Round 3
// 680.326 us; speedup vs baseline: 1.5104x; 1.1579x over previous
//
#include <hip/hip_runtime.h>
#include <hip/hip_bf16.h>

// Problem constants (from reference)
#define NN 50000
#define NE 800000
#define ET (NE + NN)          // edges + self loops = 850000
#define FIN 256
#define HC 192                // H*C = 3*64
#define NHEAD 3
#define CDIM 64
#define MAXDEG 128            // fast-path cap; Poisson(16) max over 50K nodes ~45

typedef short short8 __attribute__((ext_vector_type(8)));
typedef float f32x4 __attribute__((ext_vector_type(4)));

// ---------------------------------------------------------------------------
// CSR build: histogram -> scan -> scatter (graph shared by all 3 GAT layers)
// ---------------------------------------------------------------------------
__global__ __launch_bounds__(256) void hist_kernel(const int* __restrict__ ei,
                                                   int* __restrict__ cnt) {
    int e = blockIdx.x * 256 + threadIdx.x;
    if (e >= ET) return;
    int dst = (e < NE) ? ei[NE + e] : (e - NE);
    atomicAdd(&cnt[dst], 1);
}

#define SCAN_BLK 1024
__global__ __launch_bounds__(SCAN_BLK) void scan1_kernel(const int* __restrict__ cnt,
                                                         int* __restrict__ row_ptr,
                                                         int* __restrict__ partials) {
    __shared__ int sm[SCAN_BLK];
    int t = threadIdx.x;
    int g = blockIdx.x * SCAN_BLK + t;
    int v = (g < NN) ? cnt[g] : 0;
    sm[t] = v;
    __syncthreads();
    for (int off = 1; off < SCAN_BLK; off <<= 1) {
        int u = (t >= off) ? sm[t - off] : 0;
        __syncthreads();
        sm[t] += u;
        __syncthreads();
    }
    if (g < NN) row_ptr[g + 1] = sm[t];
    if (t == SCAN_BLK - 1) partials[blockIdx.x] = sm[t];
}

__global__ __launch_bounds__(64) void scan2_kernel(int* __restrict__ partials, int nb) {
    int t = threadIdx.x;
    int v = (t < nb) ? partials[t] : 0;
    int x = v;
    for (int off = 1; off < 64; off <<= 1) {
        int y = __shfl_up(x, off);
        if (t >= off) x += y;
    }
    if (t < nb) partials[t] = x - v;
}

__global__ __launch_bounds__(SCAN_BLK) void scan3_kernel(int* __restrict__ row_ptr,
                                                         const int* __restrict__ partials) {
    int g = blockIdx.x * SCAN_BLK + threadIdx.x;
    if (g < NN) row_ptr[g + 1] += partials[blockIdx.x];
    if (g == 0) row_ptr[0] = 0;
}

__global__ __launch_bounds__(256) void scatter_kernel(const int* __restrict__ ei,
                                                      int* __restrict__ cnt,
                                                      const int* __restrict__ row_ptr,
                                                      int* __restrict__ csr_src) {
    int e = blockIdx.x * 256 + threadIdx.x;
    if (e >= ET) return;
    int src, dst;
    if (e < NE) { src = ei[e]; dst = ei[NE + e]; }
    else        { src = e - NE; dst = e - NE; }
    int pos = atomicAdd(&cnt[dst], 1);
    csr_src[row_ptr[dst] + pos] = src;
}

// ---------------------------------------------------------------------------
// fp32 -> bf16 split helpers
// ---------------------------------------------------------------------------
__device__ __forceinline__ unsigned short f2bf(float f) {
    unsigned int u = __float_as_uint(f);
    unsigned int r = (u + 0x7FFFu + ((u >> 16) & 1u)) >> 16;   // RNE
    return (unsigned short)r;
}
__device__ __forceinline__ float bf2f(unsigned short h) {
    return __uint_as_float(((unsigned int)h) << 16);
}

// ---------------------------------------------------------------------------
// Split-bf16 MFMA GEMM: C[M,N] = A[M,K] * B[N,K]^T (fp32 in/out, ~fp32 acc).
// BM=128, BN=64, BK=32; 256 threads = 4 waves (2x2), wave tile 64x32.
// A = Ah + Al (bf16 hi/lo); C += Ah*Bh + Ah*Bl + Al*Bh  (residual ~2^-17).
// LDS rows padded to 40 ushorts (80B): 16B-aligned b128, <=2-way banks.
// ---------------------------------------------------------------------------
#define LSTR 40
__global__ __launch_bounds__(256) void sgemm_mfma(const float* __restrict__ A,
                                                  const float* __restrict__ B,
                                                  float* __restrict__ C,
                                                  int M, int N, int K) {
    __shared__ unsigned short Ah[128 * LSTR], Al[128 * LSTR];
    __shared__ unsigned short Bh[64 * LSTR],  Bl[64 * LSTR];

    const int tid  = threadIdx.x;
    const int lane = tid & 63;
    const int wid  = tid >> 6;
    const int wm   = wid & 1;        // wave m-offset /64
    const int wn   = wid >> 1;       // wave n-offset /32
    const int quad = lane >> 4;
    const int l15  = lane & 15;
    const int m0   = blockIdx.x * 128;
    const int n0   = blockIdx.y * 64;

    // staging coords: 8 threads per 32-float row
    const int srow = tid >> 3;       // 0..31
    const int scol = (tid & 7) * 4;  // float offset

    f32x4 acc[4][2];
#pragma unroll
    for (int i = 0; i < 4; i++)
#pragma unroll
        for (int j = 0; j < 2; j++) acc[i][j] = (f32x4)(0.f);

    for (int k0 = 0; k0 < K; k0 += 32) {
        // ---- stage A tile 128x32 (4 passes of 32 rows) ----
#pragma unroll
        for (int p = 0; p < 4; p++) {
            int r = srow + p * 32;
            int gm = m0 + r;
            float4 v = make_float4(0.f, 0.f, 0.f, 0.f);
            if (gm < M) v = *reinterpret_cast<const float4*>(&A[(size_t)gm * K + k0 + scol]);
            unsigned short h0 = f2bf(v.x), h1 = f2bf(v.y), h2 = f2bf(v.z), h3 = f2bf(v.w);
            unsigned short g0 = f2bf(v.x - bf2f(h0)), g1 = f2bf(v.y - bf2f(h1));
            unsigned short g2 = f2bf(v.z - bf2f(h2)), g3 = f2bf(v.w - bf2f(h3));
            int off = r * LSTR + scol;
            *reinterpret_cast<uint2*>(&Ah[off]) =
                make_uint2((unsigned)h0 | ((unsigned)h1 << 16), (unsigned)h2 | ((unsigned)h3 << 16));
            *reinterpret_cast<uint2*>(&Al[off]) =
                make_uint2((unsigned)g0 | ((unsigned)g1 << 16), (unsigned)g2 | ((unsigned)g3 << 16));
        }
        // ---- stage B tile 64x32 (2 passes) ----
#pragma unroll
        for (int p = 0; p < 2; p++) {
            int r = srow + p * 32;
            float4 v = *reinterpret_cast<const float4*>(&B[(size_t)(n0 + r) * K + k0 + scol]);
            unsigned short h0 = f2bf(v.x), h1 = f2bf(v.y), h2 = f2bf(v.z), h3 = f2bf(v.w);
            unsigned short g0 = f2bf(v.x - bf2f(h0)), g1 = f2bf(v.y - bf2f(h1));
            unsigned short g2 = f2bf(v.z - bf2f(h2)), g3 = f2bf(v.w - bf2f(h3));
            int off = r * LSTR + scol;
            *reinterpret_cast<uint2*>(&Bh[off]) =
                make_uint2((unsigned)h0 | ((unsigned)h1 << 16), (unsigned)h2 | ((unsigned)h3 << 16));
            *reinterpret_cast<uint2*>(&Bl[off]) =
                make_uint2((unsigned)g0 | ((unsigned)g1 << 16), (unsigned)g2 | ((unsigned)g3 << 16));
        }
        __syncthreads();

        // ---- fragments & MFMA ----
        short8 afh[4], afl[4], bfh[2], bfl[2];
#pragma unroll
        for (int tm = 0; tm < 4; tm++) {
            int off = (wm * 64 + tm * 16 + l15) * LSTR + quad * 8;
            afh[tm] = *reinterpret_cast<const short8*>(&Ah[off]);
            afl[tm] = *reinterpret_cast<const short8*>(&Al[off]);
        }
#pragma unroll
        for (int tn = 0; tn < 2; tn++) {
            int off = (wn * 32 + tn * 16 + l15) * LSTR + quad * 8;
            bfh[tn] = *reinterpret_cast<const short8*>(&Bh[off]);
            bfl[tn] = *reinterpret_cast<const short8*>(&Bl[off]);
        }
#pragma unroll
        for (int tm = 0; tm < 4; tm++)
#pragma unroll
            for (int tn = 0; tn < 2; tn++) {
                acc[tm][tn] = __builtin_amdgcn_mfma_f32_16x16x32_bf16(afh[tm], bfh[tn], acc[tm][tn], 0, 0, 0);
                acc[tm][tn] = __builtin_amdgcn_mfma_f32_16x16x32_bf16(afh[tm], bfl[tn], acc[tm][tn], 0, 0, 0);
                acc[tm][tn] = __builtin_amdgcn_mfma_f32_16x16x32_bf16(afl[tm], bfh[tn], acc[tm][tn], 0, 0, 0);
            }
        __syncthreads();
    }

    // ---- store: D row = quad*4+reg, col = l15 (per 16x16 tile) ----
#pragma unroll
    for (int tm = 0; tm < 4; tm++) {
        int rbase = m0 + wm * 64 + tm * 16 + quad * 4;
#pragma unroll
        for (int r = 0; r < 4; r++) {
            int row = rbase + r;
            if (row < M) {
#pragma unroll
                for (int tn = 0; tn < 2; tn++) {
                    int col = n0 + wn * 32 + tn * 16 + l15;
                    C[(size_t)row * N + col] = acc[tm][tn][r];
                }
            }
        }
    }
}

// ---------------------------------------------------------------------------
// Attention logits: al_src[n,h] = sum_c h[n,h,c]*a_src[h,c]; same for dst.
// ---------------------------------------------------------------------------
__global__ __launch_bounds__(256) void al_kernel(const float* __restrict__ h,
                                                 const float* __restrict__ a_src,
                                                 const float* __restrict__ a_dst,
                                                 float* __restrict__ al_src,
                                                 float* __restrict__ al_dst) {
    int wid = (blockIdx.x * 256 + threadIdx.x) >> 6;
    int lane = threadIdx.x & 63;
    if (wid >= NN * NHEAD) return;
    int n = wid / 3;
    int head = wid - n * 3;
    float v = h[(size_t)n * HC + head * CDIM + lane];
    float ps = v * a_src[head * CDIM + lane];
    float pd = v * a_dst[head * CDIM + lane];
#pragma unroll
    for (int off = 32; off; off >>= 1) {
        ps += __shfl_xor(ps, off);
        pd += __shfl_xor(pd, off);
    }
    if (lane == 0) { al_src[wid] = ps; al_dst[wid] = pd; }
}

// ---------------------------------------------------------------------------
// Per-wave softmax weights into LDS; returns softmax denominator.
// ---------------------------------------------------------------------------
__device__ __forceinline__ float edge_weights(const int* slds, float* wrow,
                                              const float* __restrict__ al_s,
                                              float ad, int head, int deg, int lane) {
    float m = -1e30f;
    for (int j = lane; j < deg; j += 64) {
        float a = al_s[slds[j] * 3 + head] + ad;
        a = a > 0.f ? a : 0.2f * a;
        wrow[j] = a;
        m = fmaxf(m, a);
    }
#pragma unroll
    for (int off = 32; off; off >>= 1) m = fmaxf(m, __shfl_xor(m, off));
    float ssum = 0.f;
    for (int j = lane; j < deg; j += 64) {
        float w = __expf(wrow[j] - m);
        wrow[j] = w;
        ssum += w;
    }
#pragma unroll
    for (int off = 32; off; off >>= 1) ssum += __shfl_xor(ssum, off);
    return ssum;
}

// Weighted gather-accumulate, 4-way unrolled for memory-level parallelism.
__device__ __forceinline__ float gather_acc(const int* slds, const float* wrow,
                                            const float* __restrict__ h,
                                            int head, int deg, int lane) {
    float acc = 0.f;
    int j = 0;
    for (; j + 4 <= deg; j += 4) {
        int s0 = slds[j], s1 = slds[j + 1], s2 = slds[j + 2], s3 = slds[j + 3];
        float w0 = wrow[j], w1 = wrow[j + 1], w2 = wrow[j + 2], w3 = wrow[j + 3];
        float h0 = h[(size_t)s0 * HC + head * CDIM + lane];
        float h1 = h[(size_t)s1 * HC + head * CDIM + lane];
        float h2 = h[(size_t)s2 * HC + head * CDIM + lane];
        float h3 = h[(size_t)s3 * HC + head * CDIM + lane];
        acc = fmaf(w0, h0, acc);
        acc = fmaf(w1, h1, acc);
        acc = fmaf(w2, h2, acc);
        acc = fmaf(w3, h3, acc);
    }
    for (; j < deg; ++j)
        acc = fmaf(wrow[j], h[(size_t)slds[j] * HC + head * CDIM + lane], acc);
    return acc;
}

// ---------------------------------------------------------------------------
// Layer-1 aggregation (concat + bias + relu). 3 waves/node, lane = channel.
// ---------------------------------------------------------------------------
__global__ __launch_bounds__(192) void agg_cat_kernel(const int* __restrict__ row_ptr,
                                                      const int* __restrict__ csr_src,
                                                      const float* __restrict__ h,
                                                      const float* __restrict__ al_src,
                                                      const float* __restrict__ al_dst,
                                                      const float* __restrict__ bias,
                                                      float* __restrict__ out) {
    __shared__ int slds[MAXDEG];
    __shared__ float wlds[3][MAXDEG];
    int n = blockIdx.x;
    int head = threadIdx.x >> 6;
    int lane = threadIdx.x & 63;
    int start = row_ptr[n];
    int deg = row_ptr[n + 1] - start;
    float ad = al_dst[n * 3 + head];
    float acc, ssum;

    if (deg <= MAXDEG) {
        if (threadIdx.x < deg) slds[threadIdx.x] = csr_src[start + threadIdx.x];
        __syncthreads();
        ssum = edge_weights(slds, wlds[head], al_src, ad, head, deg, lane);
        acc = gather_acc(slds, wlds[head], h, head, deg, lane);
    } else {  // streaming fallback (never hit for this graph; correctness-safe)
        float m = -1e30f;
        for (int j = start + lane; j < start + deg; j += 64) {
            float a = al_src[csr_src[j] * 3 + head] + ad;
            a = a > 0.f ? a : 0.2f * a;
            m = fmaxf(m, a);
        }
#pragma unroll
        for (int off = 32; off; off >>= 1) m = fmaxf(m, __shfl_xor(m, off));
        acc = 0.f; ssum = 0.f;
        for (int j = start; j < start + deg; ++j) {
            int s = csr_src[j];
            float a = al_src[s * 3 + head] + ad;
            a = a > 0.f ? a : 0.2f * a;
            float w = __expf(a - m);
            ssum += w;
            acc = fmaf(w, h[(size_t)s * HC + head * CDIM + lane], acc);
        }
    }
    float o = acc / (ssum + 1e-16f) + bias[head * CDIM + lane];
    out[(size_t)n * HC + head * CDIM + lane] = fmaxf(o, 0.f);
}

// ---------------------------------------------------------------------------
// mu/lv aggregation fused: 6 waves/node (3 mu + 3 lv heads), mean over heads.
// ---------------------------------------------------------------------------
__global__ __launch_bounds__(384) void agg_mean2_kernel(const int* __restrict__ row_ptr,
                                                        const int* __restrict__ csr_src,
                                                        const float* __restrict__ h_mu,
                                                        const float* __restrict__ h_lv,
                                                        const float* __restrict__ alms,
                                                        const float* __restrict__ almd,
                                                        const float* __restrict__ alls,
                                                        const float* __restrict__ alld,
                                                        const float* __restrict__ b_mu,
                                                        const float* __restrict__ b_lv,
                                                        float* __restrict__ out) {
    __shared__ int slds[MAXDEG];
    __shared__ float wlds[6][MAXDEG];
    __shared__ float red[6][64];
    int n = blockIdx.x;
    int hh = threadIdx.x >> 6;     // 0..5
    int lane = threadIdx.x & 63;
    int head = (hh < 3) ? hh : hh - 3;
    const float* h  = (hh < 3) ? h_mu : h_lv;
    const float* as = (hh < 3) ? alms : alls;
    const float* ap = (hh < 3) ? almd : alld;
    int start = row_ptr[n];
    int deg = row_ptr[n + 1] - start;
    float ad = ap[n * 3 + head];
    float acc, ssum;

    if (deg <= MAXDEG) {
        if (threadIdx.x < deg) slds[threadIdx.x] = csr_src[start + threadIdx.x];
        __syncthreads();
        ssum = edge_weights(slds, wlds[hh], as, ad, head, deg, lane);
        acc = gather_acc(slds, wlds[hh], h, head, deg, lane);
    } else {  // streaming fallback
        float m = -1e30f;
        for (int j = start + lane; j < start + deg; j += 64) {
            float a = as[csr_src[j] * 3 + head] + ad;
            a = a > 0.f ? a : 0.2f * a;
            m = fmaxf(m, a);
        }
#pragma unroll
        for (int off = 32; off; off >>= 1) m = fmaxf(m, __shfl_xor(m, off));
        acc = 0.f; ssum = 0.f;
        for (int j = start; j < start + deg; ++j) {
            int s = csr_src[j];
            float a = as[s * 3 + head] + ad;
            a = a > 0.f ? a : 0.2f * a;
            float w = __expf(a - m);
            ssum += w;
            acc = fmaf(w, h[(size_t)s * HC + head * CDIM + lane], acc);
        }
    }
    red[hh][lane] = acc / (ssum + 1e-16f);
    __syncthreads();
    if (threadIdx.x < 64) {
        out[(size_t)n * CDIM + lane] =
            (red[0][lane] + red[1][lane] + red[2][lane]) * (1.f / 3.f) + b_mu[lane];
    } else if (threadIdx.x < 128) {
        out[(size_t)NN * CDIM + (size_t)n * CDIM + lane] =
            (red[3][lane] + red[4][lane] + red[5][lane]) * (1.f / 3.f) + b_lv[lane];
    }
}

// ---------------------------------------------------------------------------
extern "C" void kernel_launch(void* const* d_in, const int* in_sizes, int n_in,
                              void* d_out, int out_size, void* d_ws, size_t ws_size,
                              hipStream_t stream) {
    const float* x    = (const float*)d_in[0];
    const int*   ei   = (const int*)d_in[1];
    const float* W1   = (const float*)d_in[2];
    const float* a1s  = (const float*)d_in[3];
    const float* a1d  = (const float*)d_in[4];
    const float* b1   = (const float*)d_in[5];
    const float* Wmu  = (const float*)d_in[6];
    const float* amus = (const float*)d_in[7];
    const float* amud = (const float*)d_in[8];
    const float* bmu  = (const float*)d_in[9];
    const float* Wlv  = (const float*)d_in[10];
    const float* alvs = (const float*)d_in[11];
    const float* alvd = (const float*)d_in[12];
    const float* blv  = (const float*)d_in[13];
    float* out = (float*)d_out;

    // workspace carve (256B aligned)
    size_t off = 0;
    auto carve = [&](size_t bytes) {
        void* p = (char*)d_ws + off;
        off += (bytes + 255) & ~(size_t)255;
        return p;
    };
    int*   cnt      = (int*)carve((size_t)NN * 4);
    int*   row_ptr  = (int*)carve((size_t)(NN + 1) * 4);
    int*   partials = (int*)carve(64 * 4);
    int*   csr      = (int*)carve((size_t)ET * 4);
    float* h1       = (float*)carve((size_t)NN * HC * 4);   // reused as h_mu
    float* hrelu    = (float*)carve((size_t)NN * HC * 4);
    float* h_lv     = (float*)carve((size_t)NN * HC * 4);
    float* al1s     = (float*)carve((size_t)NN * 3 * 4);
    float* al1d     = (float*)carve((size_t)NN * 3 * 4);
    float* alms     = (float*)carve((size_t)NN * 3 * 4);
    float* almd     = (float*)carve((size_t)NN * 3 * 4);
    float* alls     = (float*)carve((size_t)NN * 3 * 4);
    float* alld     = (float*)carve((size_t)NN * 3 * 4);
    float* h_mu = h1;

    const int scan_blocks = (NN + SCAN_BLK - 1) / SCAN_BLK;  // 49

    // ---- CSR build (shared by all 3 layers) ----
    hipMemsetAsync(cnt, 0, (size_t)NN * 4, stream);
    hist_kernel<<<(ET + 255) / 256, 256, 0, stream>>>(ei, cnt);
    scan1_kernel<<<scan_blocks, SCAN_BLK, 0, stream>>>(cnt, row_ptr, partials);
    scan2_kernel<<<1, 64, 0, stream>>>(partials, scan_blocks);
    scan3_kernel<<<scan_blocks, SCAN_BLK, 0, stream>>>(row_ptr, partials);
    hipMemsetAsync(cnt, 0, (size_t)NN * 4, stream);
    scatter_kernel<<<(ET + 255) / 256, 256, 0, stream>>>(ei, cnt, row_ptr, csr);

    // ---- Layer 1 ----
    dim3 g1((NN + 127) / 128, HC / 64);
    sgemm_mfma<<<g1, 256, 0, stream>>>(x, W1, h1, NN, HC, FIN);
    al_kernel<<<(NN * 3 + 3) / 4, 256, 0, stream>>>(h1, a1s, a1d, al1s, al1d);
    agg_cat_kernel<<<NN, 192, 0, stream>>>(row_ptr, csr, h1, al1s, al1d, b1, hrelu);

    // ---- Layers mu / lv ----
    sgemm_mfma<<<g1, 256, 0, stream>>>(hrelu, Wmu, h_mu, NN, HC, HC);
    sgemm_mfma<<<g1, 256, 0, stream>>>(hrelu, Wlv, h_lv, NN, HC, HC);
    al_kernel<<<(NN * 3 + 3) / 4, 256, 0, stream>>>(h_mu, amus, amud, alms, almd);
    al_kernel<<<(NN * 3 + 3) / 4, 256, 0, stream>>>(h_lv, alvs, alvd, alls, alld);
    agg_mean2_kernel<<<NN, 384, 0, stream>>>(row_ptr, csr, h_mu, h_lv,
                                             alms, almd, alls, alld, bmu, blv, out);
}

// Round 4
// 659.515 us; speedup vs baseline: 1.5580x; 1.0316x over previous
//
#include <hip/hip_runtime.h>
#include <hip/hip_bf16.h>
#include <hip/hip_fp16.h>

// Problem constants (from reference)
#define NN 50000
#define NE 800000
#define ET (NE + NN)          // edges + self loops = 850000
#define FIN 256
#define HC 192                // H*C = 3*64
#define NHEAD 3
#define CDIM 64
#define MAXDEG 128            // fast-path cap; Poisson(16) max over 50K nodes ~45

typedef short short8 __attribute__((ext_vector_type(8)));
typedef float f32x4 __attribute__((ext_vector_type(4)));

// ---------------------------------------------------------------------------
// CSR build: histogram -> scan -> scatter (graph shared by all 3 GAT layers)
// ---------------------------------------------------------------------------
__global__ __launch_bounds__(256) void hist_kernel(const int* __restrict__ ei,
                                                   int* __restrict__ cnt) {
    int e = blockIdx.x * 256 + threadIdx.x;
    if (e >= ET) return;
    int dst = (e < NE) ? ei[NE + e] : (e - NE);
    atomicAdd(&cnt[dst], 1);
}

#define SCAN_BLK 1024
__global__ __launch_bounds__(SCAN_BLK) void scan1_kernel(const int* __restrict__ cnt,
                                                         int* __restrict__ row_ptr,
                                                         int* __restrict__ partials) {
    __shared__ int sm[SCAN_BLK];
    int t = threadIdx.x;
    int g = blockIdx.x * SCAN_BLK + t;
    int v = (g < NN) ? cnt[g] : 0;
    sm[t] = v;
    __syncthreads();
    for (int off = 1; off < SCAN_BLK; off <<= 1) {
        int u = (t >= off) ? sm[t - off] : 0;
        __syncthreads();
        sm[t] += u;
        __syncthreads();
    }
    if (g < NN) row_ptr[g + 1] = sm[t];
    if (t == SCAN_BLK - 1) partials[blockIdx.x] = sm[t];
}

__global__ __launch_bounds__(64) void scan2_kernel(int* __restrict__ partials, int nb) {
    int t = threadIdx.x;
    int v = (t < nb) ? partials[t] : 0;
    int x = v;
    for (int off = 1; off < 64; off <<= 1) {
        int y = __shfl_up(x, off);
        if (t >= off) x += y;
    }
    if (t < nb) partials[t] = x - v;
}

__global__ __launch_bounds__(SCAN_BLK) void scan3_kernel(int* __restrict__ row_ptr,
                                                         const int* __restrict__ partials) {
    int g = blockIdx.x * SCAN_BLK + threadIdx.x;
    if (g < NN) row_ptr[g + 1] += partials[blockIdx.x];
    if (g == 0) row_ptr[0] = 0;
}

__global__ __launch_bounds__(256) void scatter_kernel(const int* __restrict__ ei,
                                                      int* __restrict__ cnt,
                                                      const int* __restrict__ row_ptr,
                                                      int* __restrict__ csr_src) {
    int e = blockIdx.x * 256 + threadIdx.x;
    if (e >= ET) return;
    int src, dst;
    if (e < NE) { src = ei[e]; dst = ei[NE + e]; }
    else        { src = e - NE; dst = e - NE; }
    int pos = atomicAdd(&cnt[dst], 1);
    csr_src[row_ptr[dst] + pos] = src;
}

// ---------------------------------------------------------------------------
// fp32 -> bf16 split helpers
// ---------------------------------------------------------------------------
__device__ __forceinline__ unsigned short f2bf(float f) {
    unsigned int u = __float_as_uint(f);
    unsigned int r = (u + 0x7FFFu + ((u >> 16) & 1u)) >> 16;   // RNE
    return (unsigned short)r;
}
__device__ __forceinline__ float bf2f(unsigned short h) {
    return __uint_as_float(((unsigned int)h) << 16);
}

__device__ __forceinline__ void storeC(float v, float* p) { *p = v; }
__device__ __forceinline__ void storeC(float v, __half* p) { *p = __float2half(v); }

// ---------------------------------------------------------------------------
// Split-bf16 MFMA GEMM: C[M,N] = A[M,K] * B[N,K]^T (fp32 in, ~fp32 acc).
// Output type templated: fp32 (layer 1) or fp16 (mu/lv, gathered later).
// BM=128, BN=64, BK=32; 256 threads = 4 waves (2x2), wave tile 64x32.
// ---------------------------------------------------------------------------
#define LSTR 40
template <typename OutT>
__global__ __launch_bounds__(256) void sgemm_mfma(const float* __restrict__ A,
                                                  const float* __restrict__ B,
                                                  OutT* __restrict__ C,
                                                  int M, int N, int K) {
    __shared__ unsigned short Ah[128 * LSTR], Al[128 * LSTR];
    __shared__ unsigned short Bh[64 * LSTR],  Bl[64 * LSTR];

    const int tid  = threadIdx.x;
    const int lane = tid & 63;
    const int wid  = tid >> 6;
    const int wm   = wid & 1;
    const int wn   = wid >> 1;
    const int quad = lane >> 4;
    const int l15  = lane & 15;
    const int m0   = blockIdx.x * 128;
    const int n0   = blockIdx.y * 64;

    const int srow = tid >> 3;       // 0..31
    const int scol = (tid & 7) * 4;  // float offset

    f32x4 acc[4][2];
#pragma unroll
    for (int i = 0; i < 4; i++)
#pragma unroll
        for (int j = 0; j < 2; j++) acc[i][j] = (f32x4)(0.f);

    for (int k0 = 0; k0 < K; k0 += 32) {
#pragma unroll
        for (int p = 0; p < 4; p++) {
            int r = srow + p * 32;
            int gm = m0 + r;
            float4 v = make_float4(0.f, 0.f, 0.f, 0.f);
            if (gm < M) v = *reinterpret_cast<const float4*>(&A[(size_t)gm * K + k0 + scol]);
            unsigned short h0 = f2bf(v.x), h1 = f2bf(v.y), h2 = f2bf(v.z), h3 = f2bf(v.w);
            unsigned short g0 = f2bf(v.x - bf2f(h0)), g1 = f2bf(v.y - bf2f(h1));
            unsigned short g2 = f2bf(v.z - bf2f(h2)), g3 = f2bf(v.w - bf2f(h3));
            int off = r * LSTR + scol;
            *reinterpret_cast<uint2*>(&Ah[off]) =
                make_uint2((unsigned)h0 | ((unsigned)h1 << 16), (unsigned)h2 | ((unsigned)h3 << 16));
            *reinterpret_cast<uint2*>(&Al[off]) =
                make_uint2((unsigned)g0 | ((unsigned)g1 << 16), (unsigned)g2 | ((unsigned)g3 << 16));
        }
#pragma unroll
        for (int p = 0; p < 2; p++) {
            int r = srow + p * 32;
            float4 v = *reinterpret_cast<const float4*>(&B[(size_t)(n0 + r) * K + k0 + scol]);
            unsigned short h0 = f2bf(v.x), h1 = f2bf(v.y), h2 = f2bf(v.z), h3 = f2bf(v.w);
            unsigned short g0 = f2bf(v.x - bf2f(h0)), g1 = f2bf(v.y - bf2f(h1));
            unsigned short g2 = f2bf(v.z - bf2f(h2)), g3 = f2bf(v.w - bf2f(h3));
            int off = r * LSTR + scol;
            *reinterpret_cast<uint2*>(&Bh[off]) =
                make_uint2((unsigned)h0 | ((unsigned)h1 << 16), (unsigned)h2 | ((unsigned)h3 << 16));
            *reinterpret_cast<uint2*>(&Bl[off]) =
                make_uint2((unsigned)g0 | ((unsigned)g1 << 16), (unsigned)g2 | ((unsigned)g3 << 16));
        }
        __syncthreads();

        short8 afh[4], afl[4], bfh[2], bfl[2];
#pragma unroll
        for (int tm = 0; tm < 4; tm++) {
            int off = (wm * 64 + tm * 16 + l15) * LSTR + quad * 8;
            afh[tm] = *reinterpret_cast<const short8*>(&Ah[off]);
            afl[tm] = *reinterpret_cast<const short8*>(&Al[off]);
        }
#pragma unroll
        for (int tn = 0; tn < 2; tn++) {
            int off = (wn * 32 + tn * 16 + l15) * LSTR + quad * 8;
            bfh[tn] = *reinterpret_cast<const short8*>(&Bh[off]);
            bfl[tn] = *reinterpret_cast<const short8*>(&Bl[off]);
        }
#pragma unroll
        for (int tm = 0; tm < 4; tm++)
#pragma unroll
            for (int tn = 0; tn < 2; tn++) {
                acc[tm][tn] = __builtin_amdgcn_mfma_f32_16x16x32_bf16(afh[tm], bfh[tn], acc[tm][tn], 0, 0, 0);
                acc[tm][tn] = __builtin_amdgcn_mfma_f32_16x16x32_bf16(afh[tm], bfl[tn], acc[tm][tn], 0, 0, 0);
                acc[tm][tn] = __builtin_amdgcn_mfma_f32_16x16x32_bf16(afl[tm], bfh[tn], acc[tm][tn], 0, 0, 0);
            }
        __syncthreads();
    }

#pragma unroll
    for (int tm = 0; tm < 4; tm++) {
        int rbase = m0 + wm * 64 + tm * 16 + quad * 4;
#pragma unroll
        for (int r = 0; r < 4; r++) {
            int row = rbase + r;
            if (row < M) {
#pragma unroll
                for (int tn = 0; tn < 2; tn++) {
                    int col = n0 + wn * 32 + tn * 16 + l15;
                    storeC(acc[tm][tn][r], &C[(size_t)row * N + col]);
                }
            }
        }
    }
}

// ---------------------------------------------------------------------------
// Attention logits (fp32 h): al[n,h] = sum_c h[n,h,c]*a[h,c]
// ---------------------------------------------------------------------------
__global__ __launch_bounds__(256) void al_kernel(const float* __restrict__ h,
                                                 const float* __restrict__ a_src,
                                                 const float* __restrict__ a_dst,
                                                 float* __restrict__ al_src,
                                                 float* __restrict__ al_dst) {
    int wid = (blockIdx.x * 256 + threadIdx.x) >> 6;
    int lane = threadIdx.x & 63;
    if (wid >= NN * NHEAD) return;
    int n = wid / 3;
    int head = wid - n * 3;
    float v = h[(size_t)n * HC + head * CDIM + lane];
    float ps = v * a_src[head * CDIM + lane];
    float pd = v * a_dst[head * CDIM + lane];
#pragma unroll
    for (int off = 32; off; off >>= 1) {
        ps += __shfl_xor(ps, off);
        pd += __shfl_xor(pd, off);
    }
    if (lane == 0) { al_src[wid] = ps; al_dst[wid] = pd; }
}

// fp16-h variant
__global__ __launch_bounds__(256) void al_h_kernel(const __half* __restrict__ h,
                                                   const float* __restrict__ a_src,
                                                   const float* __restrict__ a_dst,
                                                   float* __restrict__ al_src,
                                                   float* __restrict__ al_dst) {
    int wid = (blockIdx.x * 256 + threadIdx.x) >> 6;
    int lane = threadIdx.x & 63;
    if (wid >= NN * NHEAD) return;
    int n = wid / 3;
    int head = wid - n * 3;
    float v = __half2float(h[(size_t)n * HC + head * CDIM + lane]);
    float ps = v * a_src[head * CDIM + lane];
    float pd = v * a_dst[head * CDIM + lane];
#pragma unroll
    for (int off = 32; off; off >>= 1) {
        ps += __shfl_xor(ps, off);
        pd += __shfl_xor(pd, off);
    }
    if (lane == 0) { al_src[wid] = ps; al_dst[wid] = pd; }
}

// ---------------------------------------------------------------------------
// Per-wave softmax weights into LDS; returns softmax denominator.
// slds3[j] = src*3 precomputed once per block.
// ---------------------------------------------------------------------------
__device__ __forceinline__ float edge_weights(const int* slds3, float* wrow,
                                              const float* __restrict__ al_s,
                                              float ad, int head, int deg, int lane) {
    float m = -1e30f;
    for (int j = lane; j < deg; j += 64) {
        float a = al_s[slds3[j] + head] + ad;
        a = a > 0.f ? a : 0.2f * a;
        wrow[j] = a;
        m = fmaxf(m, a);
    }
#pragma unroll
    for (int off = 32; off; off >>= 1) m = fmaxf(m, __shfl_xor(m, off));
    float ssum = 0.f;
    for (int j = lane; j < deg; j += 64) {
        float w = __expf(wrow[j] - m);
        wrow[j] = w;
        ssum += w;
    }
#pragma unroll
    for (int off = 32; off; off >>= 1) ssum += __shfl_xor(ssum, off);
    return ssum;
}

// fp32 gather-accumulate (layer 1); sldsHC[j] = src*HC precomputed.
__device__ __forceinline__ float gather_acc(const int* sldsHC, const float* wrow,
                                            const float* __restrict__ h,
                                            int hoff, int deg) {
    float acc = 0.f;
    int j = 0;
    for (; j + 4 <= deg; j += 4) {
        int s0 = sldsHC[j], s1 = sldsHC[j + 1], s2 = sldsHC[j + 2], s3 = sldsHC[j + 3];
        float w0 = wrow[j], w1 = wrow[j + 1], w2 = wrow[j + 2], w3 = wrow[j + 3];
        float h0 = h[s0 + hoff];
        float h1 = h[s1 + hoff];
        float h2 = h[s2 + hoff];
        float h3 = h[s3 + hoff];
        acc = fmaf(w0, h0, acc);
        acc = fmaf(w1, h1, acc);
        acc = fmaf(w2, h2, acc);
        acc = fmaf(w3, h3, acc);
    }
    for (; j < deg; ++j) acc = fmaf(wrow[j], h[sldsHC[j] + hoff], acc);
    return acc;
}

// fp16 gather-accumulate (mu/lv layers)
__device__ __forceinline__ float gather_acc_h(const int* sldsHC, const float* wrow,
                                              const __half* __restrict__ h,
                                              int hoff, int deg) {
    float acc = 0.f;
    int j = 0;
    for (; j + 4 <= deg; j += 4) {
        int s0 = sldsHC[j], s1 = sldsHC[j + 1], s2 = sldsHC[j + 2], s3 = sldsHC[j + 3];
        float w0 = wrow[j], w1 = wrow[j + 1], w2 = wrow[j + 2], w3 = wrow[j + 3];
        float h0 = __half2float(h[s0 + hoff]);
        float h1 = __half2float(h[s1 + hoff]);
        float h2 = __half2float(h[s2 + hoff]);
        float h3 = __half2float(h[s3 + hoff]);
        acc = fmaf(w0, h0, acc);
        acc = fmaf(w1, h1, acc);
        acc = fmaf(w2, h2, acc);
        acc = fmaf(w3, h3, acc);
    }
    for (; j < deg; ++j) acc = fmaf(wrow[j], __half2float(h[sldsHC[j] + hoff]), acc);
    return acc;
}

// ---------------------------------------------------------------------------
// Layer-1 aggregation (concat + bias + relu). 3 waves/node, lane = channel.
// ---------------------------------------------------------------------------
__global__ __launch_bounds__(192) void agg_cat_kernel(const int* __restrict__ row_ptr,
                                                      const int* __restrict__ csr_src,
                                                      const float* __restrict__ h,
                                                      const float* __restrict__ al_src,
                                                      const float* __restrict__ al_dst,
                                                      const float* __restrict__ bias,
                                                      float* __restrict__ out) {
    __shared__ int slds3[MAXDEG];
    __shared__ int sldsHC[MAXDEG];
    __shared__ float wlds[3][MAXDEG];
    int n = blockIdx.x;
    int head = threadIdx.x >> 6;
    int lane = threadIdx.x & 63;
    int start = row_ptr[n];
    int deg = row_ptr[n + 1] - start;
    float ad = al_dst[n * 3 + head];
    float acc, ssum;

    if (deg <= MAXDEG) {
        if (threadIdx.x < deg) {
            int s = csr_src[start + threadIdx.x];
            slds3[threadIdx.x] = s * 3;
            sldsHC[threadIdx.x] = s * HC;
        }
        __syncthreads();
        ssum = edge_weights(slds3, wlds[head], al_src, ad, head, deg, lane);
        acc = gather_acc(sldsHC, wlds[head], h, head * CDIM + lane, deg);
    } else {  // streaming fallback (not hit for this graph; correctness-safe)
        float m = -1e30f;
        for (int j = start + lane; j < start + deg; j += 64) {
            float a = al_src[csr_src[j] * 3 + head] + ad;
            a = a > 0.f ? a : 0.2f * a;
            m = fmaxf(m, a);
        }
#pragma unroll
        for (int off = 32; off; off >>= 1) m = fmaxf(m, __shfl_xor(m, off));
        acc = 0.f; ssum = 0.f;
        for (int j = start; j < start + deg; ++j) {
            int s = csr_src[j];
            float a = al_src[s * 3 + head] + ad;
            a = a > 0.f ? a : 0.2f * a;
            float w = __expf(a - m);
            ssum += w;
            acc = fmaf(w, h[(size_t)s * HC + head * CDIM + lane], acc);
        }
    }
    float o = acc / (ssum + 1e-16f) + bias[head * CDIM + lane];
    out[(size_t)n * HC + head * CDIM + lane] = fmaxf(o, 0.f);
}

// ---------------------------------------------------------------------------
// mu/lv aggregation fused: 6 waves/node (3 mu + 3 lv heads), mean over heads.
// h tensors are fp16 (halved gather traffic).
// ---------------------------------------------------------------------------
__global__ __launch_bounds__(384) void agg_mean2_kernel(const int* __restrict__ row_ptr,
                                                        const int* __restrict__ csr_src,
                                                        const __half* __restrict__ h_mu,
                                                        const __half* __restrict__ h_lv,
                                                        const float* __restrict__ alms,
                                                        const float* __restrict__ almd,
                                                        const float* __restrict__ alls,
                                                        const float* __restrict__ alld,
                                                        const float* __restrict__ b_mu,
                                                        const float* __restrict__ b_lv,
                                                        float* __restrict__ out) {
    __shared__ int slds3[MAXDEG];
    __shared__ int sldsHC[MAXDEG];
    __shared__ float wlds[6][MAXDEG];
    __shared__ float red[6][64];
    int n = blockIdx.x;
    int hh = threadIdx.x >> 6;     // 0..5
    int lane = threadIdx.x & 63;
    int head = (hh < 3) ? hh : hh - 3;
    const __half* h = (hh < 3) ? h_mu : h_lv;
    const float* as = (hh < 3) ? alms : alls;
    const float* ap = (hh < 3) ? almd : alld;
    int start = row_ptr[n];
    int deg = row_ptr[n + 1] - start;
    float ad = ap[n * 3 + head];
    float acc, ssum;

    if (deg <= MAXDEG) {
        if (threadIdx.x < deg) {
            int s = csr_src[start + threadIdx.x];
            slds3[threadIdx.x] = s * 3;
            sldsHC[threadIdx.x] = s * HC;
        }
        __syncthreads();
        ssum = edge_weights(slds3, wlds[hh], as, ad, head, deg, lane);
        acc = gather_acc_h(sldsHC, wlds[hh], h, head * CDIM + lane, deg);
    } else {  // streaming fallback
        float m = -1e30f;
        for (int j = start + lane; j < start + deg; j += 64) {
            float a = as[csr_src[j] * 3 + head] + ad;
            a = a > 0.f ? a : 0.2f * a;
            m = fmaxf(m, a);
        }
#pragma unroll
        for (int off = 32; off; off >>= 1) m = fmaxf(m, __shfl_xor(m, off));
        acc = 0.f; ssum = 0.f;
        for (int j = start; j < start + deg; ++j) {
            int s = csr_src[j];
            float a = as[s * 3 + head] + ad;
            a = a > 0.f ? a : 0.2f * a;
            float w = __expf(a - m);
            ssum += w;
            acc = fmaf(w, __half2float(h[(size_t)s * HC + head * CDIM + lane]), acc);
        }
    }
    red[hh][lane] = acc / (ssum + 1e-16f);
    __syncthreads();
    if (threadIdx.x < 64) {
        out[(size_t)n * CDIM + lane] =
            (red[0][lane] + red[1][lane] + red[2][lane]) * (1.f / 3.f) + b_mu[lane];
    } else if (threadIdx.x < 128) {
        out[(size_t)NN * CDIM + (size_t)n * CDIM + lane] =
            (red[3][lane] + red[4][lane] + red[5][lane]) * (1.f / 3.f) + b_lv[lane];
    }
}

// ---------------------------------------------------------------------------
extern "C" void kernel_launch(void* const* d_in, const int* in_sizes, int n_in,
                              void* d_out, int out_size, void* d_ws, size_t ws_size,
                              hipStream_t stream) {
    const float* x    = (const float*)d_in[0];
    const int*   ei   = (const int*)d_in[1];
    const float* W1   = (const float*)d_in[2];
    const float* a1s  = (const float*)d_in[3];
    const float* a1d  = (const float*)d_in[4];
    const float* b1   = (const float*)d_in[5];
    const float* Wmu  = (const float*)d_in[6];
    const float* amus = (const float*)d_in[7];
    const float* amud = (const float*)d_in[8];
    const float* bmu  = (const float*)d_in[9];
    const float* Wlv  = (const float*)d_in[10];
    const float* alvs = (const float*)d_in[11];
    const float* alvd = (const float*)d_in[12];
    const float* blv  = (const float*)d_in[13];
    float* out = (float*)d_out;

    // workspace carve (256B aligned)
    size_t off = 0;
    auto carve = [&](size_t bytes) {
        void* p = (char*)d_ws + off;
        off += (bytes + 255) & ~(size_t)255;
        return p;
    };
    int*    cnt      = (int*)carve((size_t)NN * 4);
    int*    row_ptr  = (int*)carve((size_t)(NN + 1) * 4);
    int*    partials = (int*)carve(64 * 4);
    int*    csr      = (int*)carve((size_t)ET * 4);
    float*  h1       = (float*)carve((size_t)NN * HC * 4);
    float*  hrelu    = (float*)carve((size_t)NN * HC * 4);
    __half* hmu16    = (__half*)carve((size_t)NN * HC * 2);
    __half* hlv16    = (__half*)carve((size_t)NN * HC * 2);
    float*  al1s     = (float*)carve((size_t)NN * 3 * 4);
    float*  al1d     = (float*)carve((size_t)NN * 3 * 4);
    float*  alms     = (float*)carve((size_t)NN * 3 * 4);
    float*  almd     = (float*)carve((size_t)NN * 3 * 4);
    float*  alls     = (float*)carve((size_t)NN * 3 * 4);
    float*  alld     = (float*)carve((size_t)NN * 3 * 4);

    const int scan_blocks = (NN + SCAN_BLK - 1) / SCAN_BLK;  // 49

    // ---- CSR build (shared by all 3 layers) ----
    hipMemsetAsync(cnt, 0, (size_t)NN * 4, stream);
    hist_kernel<<<(ET + 255) / 256, 256, 0, stream>>>(ei, cnt);
    scan1_kernel<<<scan_blocks, SCAN_BLK, 0, stream>>>(cnt, row_ptr, partials);
    scan2_kernel<<<1, 64, 0, stream>>>(partials, scan_blocks);
    scan3_kernel<<<scan_blocks, SCAN_BLK, 0, stream>>>(row_ptr, partials);
    hipMemsetAsync(cnt, 0, (size_t)NN * 4, stream);
    scatter_kernel<<<(ET + 255) / 256, 256, 0, stream>>>(ei, cnt, row_ptr, csr);

    // ---- Layer 1 (fp32) ----
    dim3 g1((NN + 127) / 128, HC / 64);
    sgemm_mfma<float><<<g1, 256, 0, stream>>>(x, W1, h1, NN, HC, FIN);
    al_kernel<<<(NN * 3 + 3) / 4, 256, 0, stream>>>(h1, a1s, a1d, al1s, al1d);
    agg_cat_kernel<<<NN, 192, 0, stream>>>(row_ptr, csr, h1, al1s, al1d, b1, hrelu);

    // ---- Layers mu / lv (fp16 h) ----
    sgemm_mfma<__half><<<g1, 256, 0, stream>>>(hrelu, Wmu, hmu16, NN, HC, HC);
    sgemm_mfma<__half><<<g1, 256, 0, stream>>>(hrelu, Wlv, hlv16, NN, HC, HC);
    al_h_kernel<<<(NN * 3 + 3) / 4, 256, 0, stream>>>(hmu16, amus, amud, alms, almd);
    al_h_kernel<<<(NN * 3 + 3) / 4, 256, 0, stream>>>(hlv16, alvs, alvd, alls, alld);
    agg_mean2_kernel<<<NN, 384, 0, stream>>>(row_ptr, csr, hmu16, hlv16,
                                             alms, almd, alls, alld, bmu, blv, out);
}

// Round 5
// 624.737 us; speedup vs baseline: 1.6447x; 1.0557x over previous
//
#include <hip/hip_runtime.h>
#include <hip/hip_bf16.h>
#include <hip/hip_fp16.h>

// Problem constants (from reference)
#define NN 50000
#define NE 800000
#define ET (NE + NN)          // edges + self loops = 850000
#define FIN 256
#define HC 192                // H*C = 3*64
#define NHEAD 3
#define CDIM 64
#define MAXDEG 128            // fast-path cap; Poisson(16) max over 50K nodes ~45

typedef short short8 __attribute__((ext_vector_type(8)));
typedef float f32x4 __attribute__((ext_vector_type(4)));

// ---------------------------------------------------------------------------
// CSR build: histogram -> scan -> scatter (graph shared by all 3 GAT layers)
// ---------------------------------------------------------------------------
__global__ __launch_bounds__(256) void hist_kernel(const int* __restrict__ ei,
                                                   int* __restrict__ cnt) {
    int e = blockIdx.x * 256 + threadIdx.x;
    if (e >= ET) return;
    int dst = (e < NE) ? ei[NE + e] : (e - NE);
    atomicAdd(&cnt[dst], 1);
}

#define SCAN_BLK 1024
__global__ __launch_bounds__(SCAN_BLK) void scan1_kernel(const int* __restrict__ cnt,
                                                         int* __restrict__ row_ptr,
                                                         int* __restrict__ partials) {
    __shared__ int sm[SCAN_BLK];
    int t = threadIdx.x;
    int g = blockIdx.x * SCAN_BLK + t;
    int v = (g < NN) ? cnt[g] : 0;
    sm[t] = v;
    __syncthreads();
    for (int off = 1; off < SCAN_BLK; off <<= 1) {
        int u = (t >= off) ? sm[t - off] : 0;
        __syncthreads();
        sm[t] += u;
        __syncthreads();
    }
    if (g < NN) row_ptr[g + 1] = sm[t];
    if (t == SCAN_BLK - 1) partials[blockIdx.x] = sm[t];
}

__global__ __launch_bounds__(64) void scan2_kernel(int* __restrict__ partials, int nb) {
    int t = threadIdx.x;
    int v = (t < nb) ? partials[t] : 0;
    int x = v;
    for (int off = 1; off < 64; off <<= 1) {
        int y = __shfl_up(x, off);
        if (t >= off) x += y;
    }
    if (t < nb) partials[t] = x - v;
}

__global__ __launch_bounds__(SCAN_BLK) void scan3_kernel(int* __restrict__ row_ptr,
                                                         const int* __restrict__ partials) {
    int g = blockIdx.x * SCAN_BLK + threadIdx.x;
    if (g < NN) row_ptr[g + 1] += partials[blockIdx.x];
    if (g == 0) row_ptr[0] = 0;
}

__global__ __launch_bounds__(256) void scatter_kernel(const int* __restrict__ ei,
                                                      int* __restrict__ cnt,
                                                      const int* __restrict__ row_ptr,
                                                      int* __restrict__ csr_src) {
    int e = blockIdx.x * 256 + threadIdx.x;
    if (e >= ET) return;
    int src, dst;
    if (e < NE) { src = ei[e]; dst = ei[NE + e]; }
    else        { src = e - NE; dst = e - NE; }
    int pos = atomicAdd(&cnt[dst], 1);
    csr_src[row_ptr[dst] + pos] = src;
}

// ---------------------------------------------------------------------------
// fp32 -> bf16 split helpers
// ---------------------------------------------------------------------------
__device__ __forceinline__ unsigned short f2bf(float f) {
    unsigned int u = __float_as_uint(f);
    unsigned int r = (u + 0x7FFFu + ((u >> 16) & 1u)) >> 16;   // RNE
    return (unsigned short)r;
}
__device__ __forceinline__ float bf2f(unsigned short h) {
    return __uint_as_float(((unsigned int)h) << 16);
}

__device__ __forceinline__ void storeC(float v, float* p) { *p = v; }
__device__ __forceinline__ void storeC(float v, __half* p) { *p = __float2half(v); }

// ---------------------------------------------------------------------------
// Split-bf16 MFMA GEMM: C[M,N] = A[M,K] * B[N,K]^T (fp32 in, ~fp32 acc).
// ---------------------------------------------------------------------------
#define LSTR 40
template <typename OutT>
__global__ __launch_bounds__(256) void sgemm_mfma(const float* __restrict__ A,
                                                  const float* __restrict__ B,
                                                  OutT* __restrict__ C,
                                                  int M, int N, int K) {
    __shared__ unsigned short Ah[128 * LSTR], Al[128 * LSTR];
    __shared__ unsigned short Bh[64 * LSTR],  Bl[64 * LSTR];

    const int tid  = threadIdx.x;
    const int lane = tid & 63;
    const int wid  = tid >> 6;
    const int wm   = wid & 1;
    const int wn   = wid >> 1;
    const int quad = lane >> 4;
    const int l15  = lane & 15;
    const int m0   = blockIdx.x * 128;
    const int n0   = blockIdx.y * 64;

    const int srow = tid >> 3;       // 0..31
    const int scol = (tid & 7) * 4;  // float offset

    f32x4 acc[4][2];
#pragma unroll
    for (int i = 0; i < 4; i++)
#pragma unroll
        for (int j = 0; j < 2; j++) acc[i][j] = (f32x4)(0.f);

    for (int k0 = 0; k0 < K; k0 += 32) {
#pragma unroll
        for (int p = 0; p < 4; p++) {
            int r = srow + p * 32;
            int gm = m0 + r;
            float4 v = make_float4(0.f, 0.f, 0.f, 0.f);
            if (gm < M) v = *reinterpret_cast<const float4*>(&A[(size_t)gm * K + k0 + scol]);
            unsigned short h0 = f2bf(v.x), h1 = f2bf(v.y), h2 = f2bf(v.z), h3 = f2bf(v.w);
            unsigned short g0 = f2bf(v.x - bf2f(h0)), g1 = f2bf(v.y - bf2f(h1));
            unsigned short g2 = f2bf(v.z - bf2f(h2)), g3 = f2bf(v.w - bf2f(h3));
            int off = r * LSTR + scol;
            *reinterpret_cast<uint2*>(&Ah[off]) =
                make_uint2((unsigned)h0 | ((unsigned)h1 << 16), (unsigned)h2 | ((unsigned)h3 << 16));
            *reinterpret_cast<uint2*>(&Al[off]) =
                make_uint2((unsigned)g0 | ((unsigned)g1 << 16), (unsigned)g2 | ((unsigned)g3 << 16));
        }
#pragma unroll
        for (int p = 0; p < 2; p++) {
            int r = srow + p * 32;
            float4 v = *reinterpret_cast<const float4*>(&B[(size_t)(n0 + r) * K + k0 + scol]);
            unsigned short h0 = f2bf(v.x), h1 = f2bf(v.y), h2 = f2bf(v.z), h3 = f2bf(v.w);
            unsigned short g0 = f2bf(v.x - bf2f(h0)), g1 = f2bf(v.y - bf2f(h1));
            unsigned short g2 = f2bf(v.z - bf2f(h2)), g3 = f2bf(v.w - bf2f(h3));
            int off = r * LSTR + scol;
            *reinterpret_cast<uint2*>(&Bh[off]) =
                make_uint2((unsigned)h0 | ((unsigned)h1 << 16), (unsigned)h2 | ((unsigned)h3 << 16));
            *reinterpret_cast<uint2*>(&Bl[off]) =
                make_uint2((unsigned)g0 | ((unsigned)g1 << 16), (unsigned)g2 | ((unsigned)g3 << 16));
        }
        __syncthreads();

        short8 afh[4], afl[4], bfh[2], bfl[2];
#pragma unroll
        for (int tm = 0; tm < 4; tm++) {
            int off = (wm * 64 + tm * 16 + l15) * LSTR + quad * 8;
            afh[tm] = *reinterpret_cast<const short8*>(&Ah[off]);
            afl[tm] = *reinterpret_cast<const short8*>(&Al[off]);
        }
#pragma unroll
        for (int tn = 0; tn < 2; tn++) {
            int off = (wn * 32 + tn * 16 + l15) * LSTR + quad * 8;
            bfh[tn] = *reinterpret_cast<const short8*>(&Bh[off]);
            bfl[tn] = *reinterpret_cast<const short8*>(&Bl[off]);
        }
#pragma unroll
        for (int tm = 0; tm < 4; tm++)
#pragma unroll
            for (int tn = 0; tn < 2; tn++) {
                acc[tm][tn] = __builtin_amdgcn_mfma_f32_16x16x32_bf16(afh[tm], bfh[tn], acc[tm][tn], 0, 0, 0);
                acc[tm][tn] = __builtin_amdgcn_mfma_f32_16x16x32_bf16(afh[tm], bfl[tn], acc[tm][tn], 0, 0, 0);
                acc[tm][tn] = __builtin_amdgcn_mfma_f32_16x16x32_bf16(afl[tm], bfh[tn], acc[tm][tn], 0, 0, 0);
            }
        __syncthreads();
    }

#pragma unroll
    for (int tm = 0; tm < 4; tm++) {
        int rbase = m0 + wm * 64 + tm * 16 + quad * 4;
#pragma unroll
        for (int r = 0; r < 4; r++) {
            int row = rbase + r;
            if (row < M) {
#pragma unroll
                for (int tn = 0; tn < 2; tn++) {
                    int col = n0 + wn * 32 + tn * 16 + l15;
                    storeC(acc[tm][tn][r], &C[(size_t)row * N + col]);
                }
            }
        }
    }
}

// ---------------------------------------------------------------------------
// Attention logits
// ---------------------------------------------------------------------------
__global__ __launch_bounds__(256) void al_kernel(const float* __restrict__ h,
                                                 const float* __restrict__ a_src,
                                                 const float* __restrict__ a_dst,
                                                 float* __restrict__ al_src,
                                                 float* __restrict__ al_dst) {
    int wid = (blockIdx.x * 256 + threadIdx.x) >> 6;
    int lane = threadIdx.x & 63;
    if (wid >= NN * NHEAD) return;
    int n = wid / 3;
    int head = wid - n * 3;
    float v = h[(size_t)n * HC + head * CDIM + lane];
    float ps = v * a_src[head * CDIM + lane];
    float pd = v * a_dst[head * CDIM + lane];
#pragma unroll
    for (int off = 32; off; off >>= 1) {
        ps += __shfl_xor(ps, off);
        pd += __shfl_xor(pd, off);
    }
    if (lane == 0) { al_src[wid] = ps; al_dst[wid] = pd; }
}

__global__ __launch_bounds__(256) void al_h_kernel(const __half* __restrict__ h,
                                                   const float* __restrict__ a_src,
                                                   const float* __restrict__ a_dst,
                                                   float* __restrict__ al_src,
                                                   float* __restrict__ al_dst) {
    int wid = (blockIdx.x * 256 + threadIdx.x) >> 6;
    int lane = threadIdx.x & 63;
    if (wid >= NN * NHEAD) return;
    int n = wid / 3;
    int head = wid - n * 3;
    float v = __half2float(h[(size_t)n * HC + head * CDIM + lane]);
    float ps = v * a_src[head * CDIM + lane];
    float pd = v * a_dst[head * CDIM + lane];
#pragma unroll
    for (int off = 32; off; off >>= 1) {
        ps += __shfl_xor(ps, off);
        pd += __shfl_xor(pd, off);
    }
    if (lane == 0) { al_src[wid] = ps; al_dst[wid] = pd; }
}

// ---------------------------------------------------------------------------
// Per-wave softmax weights into LDS; returns softmax denominator.
// ---------------------------------------------------------------------------
__device__ __forceinline__ float edge_weights(const int* slds3, float* wrow,
                                              const float* __restrict__ al_s,
                                              float ad, int head, int deg, int lane) {
    float m = -1e30f;
    for (int j = lane; j < deg; j += 64) {
        float a = al_s[slds3[j] + head] + ad;
        a = a > 0.f ? a : 0.2f * a;
        wrow[j] = a;
        m = fmaxf(m, a);
    }
#pragma unroll
    for (int off = 32; off; off >>= 1) m = fmaxf(m, __shfl_xor(m, off));
    float ssum = 0.f;
    for (int j = lane; j < deg; j += 64) {
        float w = __expf(wrow[j] - m);
        wrow[j] = w;
        ssum += w;
    }
#pragma unroll
    for (int off = 32; off; off >>= 1) ssum += __shfl_xor(ssum, off);
    return ssum;
}

// ---------------------------------------------------------------------------
// 4-edges-per-instruction gathers. lane = (sub = edge slot 0..3, l16 = chan/4).
// Per-lane float4 partial acc over channels l16*4..+3; merged by shfl_xor(16,32).
// ---------------------------------------------------------------------------
__device__ __forceinline__ float4 gather4_f32(const int* sldsHC, const float* wrow,
                                              const float* __restrict__ h,
                                              int hoff, int deg, int sub) {
    float4 acc = make_float4(0.f, 0.f, 0.f, 0.f);
    int j = 0;
    for (; j + 8 <= deg; j += 8) {
        int sA = sldsHC[j + sub], sB = sldsHC[j + 4 + sub];
        float wA = wrow[j + sub], wB = wrow[j + 4 + sub];
        float4 vA = *reinterpret_cast<const float4*>(&h[sA + hoff]);
        float4 vB = *reinterpret_cast<const float4*>(&h[sB + hoff]);
        acc.x = fmaf(wA, vA.x, acc.x); acc.y = fmaf(wA, vA.y, acc.y);
        acc.z = fmaf(wA, vA.z, acc.z); acc.w = fmaf(wA, vA.w, acc.w);
        acc.x = fmaf(wB, vB.x, acc.x); acc.y = fmaf(wB, vB.y, acc.y);
        acc.z = fmaf(wB, vB.z, acc.z); acc.w = fmaf(wB, vB.w, acc.w);
    }
    if (j + 4 <= deg) {
        int s = sldsHC[j + sub];
        float w = wrow[j + sub];
        float4 v = *reinterpret_cast<const float4*>(&h[s + hoff]);
        acc.x = fmaf(w, v.x, acc.x); acc.y = fmaf(w, v.y, acc.y);
        acc.z = fmaf(w, v.z, acc.z); acc.w = fmaf(w, v.w, acc.w);
        j += 4;
    }
    int rem = deg - j;
    if (sub < rem) {
        int s = sldsHC[j + sub];
        float w = wrow[j + sub];
        float4 v = *reinterpret_cast<const float4*>(&h[s + hoff]);
        acc.x = fmaf(w, v.x, acc.x); acc.y = fmaf(w, v.y, acc.y);
        acc.z = fmaf(w, v.z, acc.z); acc.w = fmaf(w, v.w, acc.w);
    }
#pragma unroll
    for (int off = 16; off <= 32; off <<= 1) {
        acc.x += __shfl_xor(acc.x, off);
        acc.y += __shfl_xor(acc.y, off);
        acc.z += __shfl_xor(acc.z, off);
        acc.w += __shfl_xor(acc.w, off);
    }
    return acc;
}

__device__ __forceinline__ float4 fma4h(float w, uint2 u, float4 acc) {
    __half2 p0 = *reinterpret_cast<__half2*>(&u.x);
    __half2 p1 = *reinterpret_cast<__half2*>(&u.y);
    float2 f0 = __half22float2(p0);
    float2 f1 = __half22float2(p1);
    acc.x = fmaf(w, f0.x, acc.x); acc.y = fmaf(w, f0.y, acc.y);
    acc.z = fmaf(w, f1.x, acc.z); acc.w = fmaf(w, f1.y, acc.w);
    return acc;
}

__device__ __forceinline__ float4 gather4_f16(const int* sldsHC, const float* wrow,
                                              const __half* __restrict__ h,
                                              int hoff, int deg, int sub) {
    float4 acc = make_float4(0.f, 0.f, 0.f, 0.f);
    int j = 0;
    for (; j + 8 <= deg; j += 8) {
        int sA = sldsHC[j + sub], sB = sldsHC[j + 4 + sub];
        float wA = wrow[j + sub], wB = wrow[j + 4 + sub];
        uint2 uA = *reinterpret_cast<const uint2*>(&h[sA + hoff]);
        uint2 uB = *reinterpret_cast<const uint2*>(&h[sB + hoff]);
        acc = fma4h(wA, uA, acc);
        acc = fma4h(wB, uB, acc);
    }
    if (j + 4 <= deg) {
        int s = sldsHC[j + sub];
        float w = wrow[j + sub];
        uint2 u = *reinterpret_cast<const uint2*>(&h[s + hoff]);
        acc = fma4h(w, u, acc);
        j += 4;
    }
    int rem = deg - j;
    if (sub < rem) {
        int s = sldsHC[j + sub];
        float w = wrow[j + sub];
        uint2 u = *reinterpret_cast<const uint2*>(&h[s + hoff]);
        acc = fma4h(w, u, acc);
    }
#pragma unroll
    for (int off = 16; off <= 32; off <<= 1) {
        acc.x += __shfl_xor(acc.x, off);
        acc.y += __shfl_xor(acc.y, off);
        acc.z += __shfl_xor(acc.z, off);
        acc.w += __shfl_xor(acc.w, off);
    }
    return acc;
}

// ---------------------------------------------------------------------------
// Layer-1 aggregation (concat + bias + relu). 3 waves/node.
// ---------------------------------------------------------------------------
__global__ __launch_bounds__(192) void agg_cat_kernel(const int* __restrict__ row_ptr,
                                                      const int* __restrict__ csr_src,
                                                      const float* __restrict__ h,
                                                      const float* __restrict__ al_src,
                                                      const float* __restrict__ al_dst,
                                                      const float* __restrict__ bias,
                                                      float* __restrict__ out) {
    __shared__ int slds3[MAXDEG];
    __shared__ int sldsHC[MAXDEG];
    __shared__ float wlds[3][MAXDEG];
    int n = blockIdx.x;
    int head = threadIdx.x >> 6;
    int lane = threadIdx.x & 63;
    int start = row_ptr[n];
    int deg = row_ptr[n + 1] - start;
    float ad = al_dst[n * 3 + head];

    if (deg <= MAXDEG) {
        if (threadIdx.x < deg) {
            int s = csr_src[start + threadIdx.x];
            slds3[threadIdx.x] = s * 3;
            sldsHC[threadIdx.x] = s * HC;
        }
        __syncthreads();
        float ssum = edge_weights(slds3, wlds[head], al_src, ad, head, deg, lane);
        const int sub = lane >> 4, l16 = lane & 15;
        float4 acc = gather4_f32(sldsHC, wlds[head], h, head * CDIM + l16 * 4, deg, sub);
        if (lane < 16) {
            float inv = 1.f / (ssum + 1e-16f);
            const float4 b4 = *reinterpret_cast<const float4*>(&bias[head * CDIM + l16 * 4]);
            float4 o;
            o.x = fmaxf(fmaf(acc.x, inv, b4.x), 0.f);
            o.y = fmaxf(fmaf(acc.y, inv, b4.y), 0.f);
            o.z = fmaxf(fmaf(acc.z, inv, b4.z), 0.f);
            o.w = fmaxf(fmaf(acc.w, inv, b4.w), 0.f);
            *reinterpret_cast<float4*>(&out[(size_t)n * HC + head * CDIM + l16 * 4]) = o;
        }
    } else {  // streaming fallback (not hit for this graph; correctness-safe)
        float m = -1e30f;
        for (int j = start + lane; j < start + deg; j += 64) {
            float a = al_src[csr_src[j] * 3 + head] + ad;
            a = a > 0.f ? a : 0.2f * a;
            m = fmaxf(m, a);
        }
#pragma unroll
        for (int off = 32; off; off >>= 1) m = fmaxf(m, __shfl_xor(m, off));
        float acc = 0.f, ssum = 0.f;
        for (int j = start; j < start + deg; ++j) {
            int s = csr_src[j];
            float a = al_src[s * 3 + head] + ad;
            a = a > 0.f ? a : 0.2f * a;
            float w = __expf(a - m);
            ssum += w;
            acc = fmaf(w, h[(size_t)s * HC + head * CDIM + lane], acc);
        }
        float o = acc / (ssum + 1e-16f) + bias[head * CDIM + lane];
        out[(size_t)n * HC + head * CDIM + lane] = fmaxf(o, 0.f);
    }
}

// ---------------------------------------------------------------------------
// mu/lv aggregation fused: 6 waves/node (3 mu + 3 lv heads), mean over heads.
// ---------------------------------------------------------------------------
__global__ __launch_bounds__(384) void agg_mean2_kernel(const int* __restrict__ row_ptr,
                                                        const int* __restrict__ csr_src,
                                                        const __half* __restrict__ h_mu,
                                                        const __half* __restrict__ h_lv,
                                                        const float* __restrict__ alms,
                                                        const float* __restrict__ almd,
                                                        const float* __restrict__ alls,
                                                        const float* __restrict__ alld,
                                                        const float* __restrict__ b_mu,
                                                        const float* __restrict__ b_lv,
                                                        float* __restrict__ out) {
    __shared__ int slds3[MAXDEG];
    __shared__ int sldsHC[MAXDEG];
    __shared__ float wlds[6][MAXDEG];
    __shared__ __align__(16) float red[6][64];
    int n = blockIdx.x;
    int hh = threadIdx.x >> 6;     // 0..5
    int lane = threadIdx.x & 63;
    int head = (hh < 3) ? hh : hh - 3;
    const __half* h = (hh < 3) ? h_mu : h_lv;
    const float* as = (hh < 3) ? alms : alls;
    const float* ap = (hh < 3) ? almd : alld;
    int start = row_ptr[n];
    int deg = row_ptr[n + 1] - start;
    float ad = ap[n * 3 + head];

    if (deg <= MAXDEG) {
        if (threadIdx.x < deg) {
            int s = csr_src[start + threadIdx.x];
            slds3[threadIdx.x] = s * 3;
            sldsHC[threadIdx.x] = s * HC;
        }
        __syncthreads();
        float ssum = edge_weights(slds3, wlds[hh], as, ad, head, deg, lane);
        const int sub = lane >> 4, l16 = lane & 15;
        float4 acc = gather4_f16(sldsHC, wlds[hh], h, head * CDIM + l16 * 4, deg, sub);
        if (lane < 16) {
            float inv = 1.f / (ssum + 1e-16f);
            float4 r;
            r.x = acc.x * inv; r.y = acc.y * inv; r.z = acc.z * inv; r.w = acc.w * inv;
            *reinterpret_cast<float4*>(&red[hh][l16 * 4]) = r;
        }
    } else {  // streaming fallback
        float m = -1e30f;
        for (int j = start + lane; j < start + deg; j += 64) {
            float a = as[csr_src[j] * 3 + head] + ad;
            a = a > 0.f ? a : 0.2f * a;
            m = fmaxf(m, a);
        }
#pragma unroll
        for (int off = 32; off; off >>= 1) m = fmaxf(m, __shfl_xor(m, off));
        float acc = 0.f, ssum = 0.f;
        for (int j = start; j < start + deg; ++j) {
            int s = csr_src[j];
            float a = as[s * 3 + head] + ad;
            a = a > 0.f ? a : 0.2f * a;
            float w = __expf(a - m);
            ssum += w;
            acc = fmaf(w, __half2float(h[(size_t)s * HC + head * CDIM + lane]), acc);
        }
        red[hh][lane] = acc / (ssum + 1e-16f);
    }
    __syncthreads();
    if (threadIdx.x < 64) {
        out[(size_t)n * CDIM + lane] =
            (red[0][lane] + red[1][lane] + red[2][lane]) * (1.f / 3.f) + b_mu[lane];
    } else if (threadIdx.x < 128) {
        out[(size_t)NN * CDIM + (size_t)n * CDIM + lane] =
            (red[3][lane] + red[4][lane] + red[5][lane]) * (1.f / 3.f) + b_lv[lane];
    }
}

// ---------------------------------------------------------------------------
extern "C" void kernel_launch(void* const* d_in, const int* in_sizes, int n_in,
                              void* d_out, int out_size, void* d_ws, size_t ws_size,
                              hipStream_t stream) {
    const float* x    = (const float*)d_in[0];
    const int*   ei   = (const int*)d_in[1];
    const float* W1   = (const float*)d_in[2];
    const float* a1s  = (const float*)d_in[3];
    const float* a1d  = (const float*)d_in[4];
    const float* b1   = (const float*)d_in[5];
    const float* Wmu  = (const float*)d_in[6];
    const float* amus = (const float*)d_in[7];
    const float* amud = (const float*)d_in[8];
    const float* bmu  = (const float*)d_in[9];
    const float* Wlv  = (const float*)d_in[10];
    const float* alvs = (const float*)d_in[11];
    const float* alvd = (const float*)d_in[12];
    const float* blv  = (const float*)d_in[13];
    float* out = (float*)d_out;

    // workspace carve (256B aligned)
    size_t off = 0;
    auto carve = [&](size_t bytes) {
        void* p = (char*)d_ws + off;
        off += (bytes + 255) & ~(size_t)255;
        return p;
    };
    int*    cnt      = (int*)carve((size_t)NN * 4);
    int*    row_ptr  = (int*)carve((size_t)(NN + 1) * 4);
    int*    partials = (int*)carve(64 * 4);
    int*    csr      = (int*)carve((size_t)ET * 4);
    float*  h1       = (float*)carve((size_t)NN * HC * 4);
    float*  hrelu    = (float*)carve((size_t)NN * HC * 4);
    __half* hmu16    = (__half*)carve((size_t)NN * HC * 2);
    __half* hlv16    = (__half*)carve((size_t)NN * HC * 2);
    float*  al1s     = (float*)carve((size_t)NN * 3 * 4);
    float*  al1d     = (float*)carve((size_t)NN * 3 * 4);
    float*  alms     = (float*)carve((size_t)NN * 3 * 4);
    float*  almd     = (float*)carve((size_t)NN * 3 * 4);
    float*  alls     = (float*)carve((size_t)NN * 3 * 4);
    float*  alld     = (float*)carve((size_t)NN * 3 * 4);

    const int scan_blocks = (NN + SCAN_BLK - 1) / SCAN_BLK;  // 49

    // ---- CSR build (shared by all 3 layers) ----
    hipMemsetAsync(cnt, 0, (size_t)NN * 4, stream);
    hist_kernel<<<(ET + 255) / 256, 256, 0, stream>>>(ei, cnt);
    scan1_kernel<<<scan_blocks, SCAN_BLK, 0, stream>>>(cnt, row_ptr, partials);
    scan2_kernel<<<1, 64, 0, stream>>>(partials, scan_blocks);
    scan3_kernel<<<scan_blocks, SCAN_BLK, 0, stream>>>(row_ptr, partials);
    hipMemsetAsync(cnt, 0, (size_t)NN * 4, stream);
    scatter_kernel<<<(ET + 255) / 256, 256, 0, stream>>>(ei, cnt, row_ptr, csr);

    // ---- Layer 1 (fp32) ----
    dim3 g1((NN + 127) / 128, HC / 64);
    sgemm_mfma<float><<<g1, 256, 0, stream>>>(x, W1, h1, NN, HC, FIN);
    al_kernel<<<(NN * 3 + 3) / 4, 256, 0, stream>>>(h1, a1s, a1d, al1s, al1d);
    agg_cat_kernel<<<NN, 192, 0, stream>>>(row_ptr, csr, h1, al1s, al1d, b1, hrelu);

    // ---- Layers mu / lv (fp16 h) ----
    sgemm_mfma<__half><<<g1, 256, 0, stream>>>(hrelu, Wmu, hmu16, NN, HC, HC);
    sgemm_mfma<__half><<<g1, 256, 0, stream>>>(hrelu, Wlv, hlv16, NN, HC, HC);
    al_h_kernel<<<(NN * 3 + 3) / 4, 256, 0, stream>>>(hmu16, amus, amud, alms, almd);
    al_h_kernel<<<(NN * 3 + 3) / 4, 256, 0, stream>>>(hlv16, alvs, alvd, alls, alld);
    agg_mean2_kernel<<<NN, 384, 0, stream>>>(row_ptr, csr, hmu16, hlv16,
                                             alms, almd, alls, alld, bmu, blv, out);
}

// Round 6
// 547.607 us; speedup vs baseline: 1.8764x; 1.1409x over previous
//
#include <hip/hip_runtime.h>
#include <hip/hip_bf16.h>
#include <hip/hip_fp16.h>

// Problem constants (from reference)
#define NN 50000
#define NE 800000
#define ET (NE + NN)          // edges + self loops = 850000
#define FIN 256
#define HC 192                // H*C = 3*64
#define NHEAD 3
#define CDIM 64
#define MAXDEG 128            // fast-path cap; Poisson(17) max over 50K nodes ~45

typedef short short8 __attribute__((ext_vector_type(8)));
typedef float f32x4 __attribute__((ext_vector_type(4)));

// ---------------------------------------------------------------------------
// CSR build: histogram -> scan -> scatter (graph shared by all 3 GAT layers)
// ---------------------------------------------------------------------------
__global__ __launch_bounds__(256) void hist_kernel(const int* __restrict__ ei,
                                                   int* __restrict__ cnt) {
    int e = blockIdx.x * 256 + threadIdx.x;
    if (e >= ET) return;
    int dst = (e < NE) ? ei[NE + e] : (e - NE);
    atomicAdd(&cnt[dst], 1);
}

#define SCAN_BLK 1024
__global__ __launch_bounds__(SCAN_BLK) void scan1_kernel(const int* __restrict__ cnt,
                                                         int* __restrict__ row_ptr,
                                                         int* __restrict__ partials) {
    __shared__ int sm[SCAN_BLK];
    int t = threadIdx.x;
    int g = blockIdx.x * SCAN_BLK + t;
    int v = (g < NN) ? cnt[g] : 0;
    sm[t] = v;
    __syncthreads();
    for (int off = 1; off < SCAN_BLK; off <<= 1) {
        int u = (t >= off) ? sm[t - off] : 0;
        __syncthreads();
        sm[t] += u;
        __syncthreads();
    }
    if (g < NN) row_ptr[g + 1] = sm[t];
    if (t == SCAN_BLK - 1) partials[blockIdx.x] = sm[t];
}

__global__ __launch_bounds__(64) void scan2_kernel(int* __restrict__ partials, int nb) {
    int t = threadIdx.x;
    int v = (t < nb) ? partials[t] : 0;
    int x = v;
    for (int off = 1; off < 64; off <<= 1) {
        int y = __shfl_up(x, off);
        if (t >= off) x += y;
    }
    if (t < nb) partials[t] = x - v;
}

__global__ __launch_bounds__(SCAN_BLK) void scan3_kernel(int* __restrict__ row_ptr,
                                                         const int* __restrict__ partials) {
    int g = blockIdx.x * SCAN_BLK + threadIdx.x;
    if (g < NN) row_ptr[g + 1] += partials[blockIdx.x];
    if (g == 0) row_ptr[0] = 0;
}

__global__ __launch_bounds__(256) void scatter_kernel(const int* __restrict__ ei,
                                                      int* __restrict__ cnt,
                                                      const int* __restrict__ row_ptr,
                                                      int* __restrict__ csr_src) {
    int e = blockIdx.x * 256 + threadIdx.x;
    if (e >= ET) return;
    int src, dst;
    if (e < NE) { src = ei[e]; dst = ei[NE + e]; }
    else        { src = e - NE; dst = e - NE; }
    int pos = atomicAdd(&cnt[dst], 1);
    csr_src[row_ptr[dst] + pos] = src;
}

// ---------------------------------------------------------------------------
// fp32 -> bf16 split helpers
// ---------------------------------------------------------------------------
__device__ __forceinline__ unsigned short f2bf(float f) {
    unsigned int u = __float_as_uint(f);
    unsigned int r = (u + 0x7FFFu + ((u >> 16) & 1u)) >> 16;   // RNE
    return (unsigned short)r;
}
__device__ __forceinline__ float bf2f(unsigned short h) {
    return __uint_as_float(((unsigned int)h) << 16);
}

__device__ __forceinline__ void storeC(float v, float* p) { *p = v; }
__device__ __forceinline__ void storeC(float v, __half* p) { *p = __float2half(v); }

// ---------------------------------------------------------------------------
// Split-bf16 MFMA GEMM: C[M,N] = A[M,K] * B[N,K]^T (fp32 in, ~fp32 acc).
// ---------------------------------------------------------------------------
#define LSTR 40
template <typename OutT>
__global__ __launch_bounds__(256) void sgemm_mfma(const float* __restrict__ A,
                                                  const float* __restrict__ B,
                                                  OutT* __restrict__ C,
                                                  int M, int N, int K) {
    __shared__ unsigned short Ah[128 * LSTR], Al[128 * LSTR];
    __shared__ unsigned short Bh[64 * LSTR],  Bl[64 * LSTR];

    const int tid  = threadIdx.x;
    const int lane = tid & 63;
    const int wid  = tid >> 6;
    const int wm   = wid & 1;
    const int wn   = wid >> 1;
    const int quad = lane >> 4;
    const int l15  = lane & 15;
    const int m0   = blockIdx.x * 128;
    const int n0   = blockIdx.y * 64;

    const int srow = tid >> 3;       // 0..31
    const int scol = (tid & 7) * 4;  // float offset

    f32x4 acc[4][2];
#pragma unroll
    for (int i = 0; i < 4; i++)
#pragma unroll
        for (int j = 0; j < 2; j++) acc[i][j] = (f32x4)(0.f);

    for (int k0 = 0; k0 < K; k0 += 32) {
#pragma unroll
        for (int p = 0; p < 4; p++) {
            int r = srow + p * 32;
            int gm = m0 + r;
            float4 v = make_float4(0.f, 0.f, 0.f, 0.f);
            if (gm < M) v = *reinterpret_cast<const float4*>(&A[(size_t)gm * K + k0 + scol]);
            unsigned short h0 = f2bf(v.x), h1 = f2bf(v.y), h2 = f2bf(v.z), h3 = f2bf(v.w);
            unsigned short g0 = f2bf(v.x - bf2f(h0)), g1 = f2bf(v.y - bf2f(h1));
            unsigned short g2 = f2bf(v.z - bf2f(h2)), g3 = f2bf(v.w - bf2f(h3));
            int off = r * LSTR + scol;
            *reinterpret_cast<uint2*>(&Ah[off]) =
                make_uint2((unsigned)h0 | ((unsigned)h1 << 16), (unsigned)h2 | ((unsigned)h3 << 16));
            *reinterpret_cast<uint2*>(&Al[off]) =
                make_uint2((unsigned)g0 | ((unsigned)g1 << 16), (unsigned)g2 | ((unsigned)g3 << 16));
        }
#pragma unroll
        for (int p = 0; p < 2; p++) {
            int r = srow + p * 32;
            float4 v = *reinterpret_cast<const float4*>(&B[(size_t)(n0 + r) * K + k0 + scol]);
            unsigned short h0 = f2bf(v.x), h1 = f2bf(v.y), h2 = f2bf(v.z), h3 = f2bf(v.w);
            unsigned short g0 = f2bf(v.x - bf2f(h0)), g1 = f2bf(v.y - bf2f(h1));
            unsigned short g2 = f2bf(v.z - bf2f(h2)), g3 = f2bf(v.w - bf2f(h3));
            int off = r * LSTR + scol;
            *reinterpret_cast<uint2*>(&Bh[off]) =
                make_uint2((unsigned)h0 | ((unsigned)h1 << 16), (unsigned)h2 | ((unsigned)h3 << 16));
            *reinterpret_cast<uint2*>(&Bl[off]) =
                make_uint2((unsigned)g0 | ((unsigned)g1 << 16), (unsigned)g2 | ((unsigned)g3 << 16));
        }
        __syncthreads();

        short8 afh[4], afl[4], bfh[2], bfl[2];
#pragma unroll
        for (int tm = 0; tm < 4; tm++) {
            int off = (wm * 64 + tm * 16 + l15) * LSTR + quad * 8;
            afh[tm] = *reinterpret_cast<const short8*>(&Ah[off]);
            afl[tm] = *reinterpret_cast<const short8*>(&Al[off]);
        }
#pragma unroll
        for (int tn = 0; tn < 2; tn++) {
            int off = (wn * 32 + tn * 16 + l15) * LSTR + quad * 8;
            bfh[tn] = *reinterpret_cast<const short8*>(&Bh[off]);
            bfl[tn] = *reinterpret_cast<const short8*>(&Bl[off]);
        }
#pragma unroll
        for (int tm = 0; tm < 4; tm++)
#pragma unroll
            for (int tn = 0; tn < 2; tn++) {
                acc[tm][tn] = __builtin_amdgcn_mfma_f32_16x16x32_bf16(afh[tm], bfh[tn], acc[tm][tn], 0, 0, 0);
                acc[tm][tn] = __builtin_amdgcn_mfma_f32_16x16x32_bf16(afh[tm], bfl[tn], acc[tm][tn], 0, 0, 0);
                acc[tm][tn] = __builtin_amdgcn_mfma_f32_16x16x32_bf16(afl[tm], bfh[tn], acc[tm][tn], 0, 0, 0);
            }
        __syncthreads();
    }

#pragma unroll
    for (int tm = 0; tm < 4; tm++) {
        int rbase = m0 + wm * 64 + tm * 16 + quad * 4;
#pragma unroll
        for (int r = 0; r < 4; r++) {
            int row = rbase + r;
            if (row < M) {
#pragma unroll
                for (int tn = 0; tn < 2; tn++) {
                    int col = n0 + wn * 32 + tn * 16 + l15;
                    storeC(acc[tm][tn][r], &C[(size_t)row * N + col]);
                }
            }
        }
    }
}

// ---------------------------------------------------------------------------
// Attention logits (fp16 h)
// ---------------------------------------------------------------------------
__global__ __launch_bounds__(256) void al_h_kernel(const __half* __restrict__ h,
                                                   const float* __restrict__ a_src,
                                                   const float* __restrict__ a_dst,
                                                   float* __restrict__ al_src,
                                                   float* __restrict__ al_dst) {
    int wid = (blockIdx.x * 256 + threadIdx.x) >> 6;
    int lane = threadIdx.x & 63;
    if (wid >= NN * NHEAD) return;
    int n = wid / 3;
    int head = wid - n * 3;
    float v = __half2float(h[(size_t)n * HC + head * CDIM + lane]);
    float ps = v * a_src[head * CDIM + lane];
    float pd = v * a_dst[head * CDIM + lane];
#pragma unroll
    for (int off = 32; off; off >>= 1) {
        ps += __shfl_xor(ps, off);
        pd += __shfl_xor(pd, off);
    }
    if (lane == 0) { al_src[wid] = ps; al_dst[wid] = pd; }
}

// ---------------------------------------------------------------------------
// Per-wave softmax weights into LDS; returns softmax denominator.
// ---------------------------------------------------------------------------
__device__ __forceinline__ float edge_weights(const int* slds3, float* wrow,
                                              const float* __restrict__ al_s,
                                              float ad, int head, int deg, int lane) {
    float m = -1e30f;
    for (int j = lane; j < deg; j += 64) {
        float a = al_s[slds3[j] + head] + ad;
        a = a > 0.f ? a : 0.2f * a;
        wrow[j] = a;
        m = fmaxf(m, a);
    }
#pragma unroll
    for (int off = 32; off; off >>= 1) m = fmaxf(m, __shfl_xor(m, off));
    float ssum = 0.f;
    for (int j = lane; j < deg; j += 64) {
        float w = __expf(wrow[j] - m);
        wrow[j] = w;
        ssum += w;
    }
#pragma unroll
    for (int off = 32; off; off >>= 1) ssum += __shfl_xor(ssum, off);
    return ssum;
}

// ---------------------------------------------------------------------------
// fp16 4-edges-per-instruction gather. lane = (sub = edge slot, l16 = chan/4).
// ---------------------------------------------------------------------------
__device__ __forceinline__ float4 fma4h(float w, uint2 u, float4 acc) {
    __half2 p0 = *reinterpret_cast<__half2*>(&u.x);
    __half2 p1 = *reinterpret_cast<__half2*>(&u.y);
    float2 f0 = __half22float2(p0);
    float2 f1 = __half22float2(p1);
    acc.x = fmaf(w, f0.x, acc.x); acc.y = fmaf(w, f0.y, acc.y);
    acc.z = fmaf(w, f1.x, acc.z); acc.w = fmaf(w, f1.y, acc.w);
    return acc;
}

__device__ __forceinline__ float4 gather4_f16(const int* sldsHC, const float* wrow,
                                              const __half* __restrict__ h,
                                              int hoff, int deg, int sub) {
    float4 acc = make_float4(0.f, 0.f, 0.f, 0.f);
    int j = 0;
    for (; j + 8 <= deg; j += 8) {
        int sA = sldsHC[j + sub], sB = sldsHC[j + 4 + sub];
        float wA = wrow[j + sub], wB = wrow[j + 4 + sub];
        uint2 uA = *reinterpret_cast<const uint2*>(&h[sA + hoff]);
        uint2 uB = *reinterpret_cast<const uint2*>(&h[sB + hoff]);
        acc = fma4h(wA, uA, acc);
        acc = fma4h(wB, uB, acc);
    }
    if (j + 4 <= deg) {
        int s = sldsHC[j + sub];
        float w = wrow[j + sub];
        uint2 u = *reinterpret_cast<const uint2*>(&h[s + hoff]);
        acc = fma4h(w, u, acc);
        j += 4;
    }
    int rem = deg - j;
    if (sub < rem) {
        int s = sldsHC[j + sub];
        float w = wrow[j + sub];
        uint2 u = *reinterpret_cast<const uint2*>(&h[s + hoff]);
        acc = fma4h(w, u, acc);
    }
#pragma unroll
    for (int off = 16; off <= 32; off <<= 1) {
        acc.x += __shfl_xor(acc.x, off);
        acc.y += __shfl_xor(acc.y, off);
        acc.z += __shfl_xor(acc.z, off);
        acc.w += __shfl_xor(acc.w, off);
    }
    return acc;
}

// ---------------------------------------------------------------------------
// Layer-1 aggregation (concat + bias + relu). 3 waves/node, fp16 h gathers.
// ---------------------------------------------------------------------------
__global__ __launch_bounds__(192) void agg_cat_kernel(const int* __restrict__ row_ptr,
                                                      const int* __restrict__ csr_src,
                                                      const __half* __restrict__ h,
                                                      const float* __restrict__ al_src,
                                                      const float* __restrict__ al_dst,
                                                      const float* __restrict__ bias,
                                                      float* __restrict__ out) {
    __shared__ int slds3[MAXDEG];
    __shared__ int sldsHC[MAXDEG];
    __shared__ float wlds[3][MAXDEG];
    int n = blockIdx.x;
    int head = threadIdx.x >> 6;
    int lane = threadIdx.x & 63;
    int start = row_ptr[n];
    int deg = row_ptr[n + 1] - start;
    float ad = al_dst[n * 3 + head];

    if (deg <= MAXDEG) {
        if (threadIdx.x < deg) {
            int s = csr_src[start + threadIdx.x];
            slds3[threadIdx.x] = s * 3;
            sldsHC[threadIdx.x] = s * HC;
        }
        __syncthreads();
        float ssum = edge_weights(slds3, wlds[head], al_src, ad, head, deg, lane);
        const int sub = lane >> 4, l16 = lane & 15;
        float4 acc = gather4_f16(sldsHC, wlds[head], h, head * CDIM + l16 * 4, deg, sub);
        if (lane < 16) {
            float inv = 1.f / (ssum + 1e-16f);
            const float4 b4 = *reinterpret_cast<const float4*>(&bias[head * CDIM + l16 * 4]);
            float4 o;
            o.x = fmaxf(fmaf(acc.x, inv, b4.x), 0.f);
            o.y = fmaxf(fmaf(acc.y, inv, b4.y), 0.f);
            o.z = fmaxf(fmaf(acc.z, inv, b4.z), 0.f);
            o.w = fmaxf(fmaf(acc.w, inv, b4.w), 0.f);
            *reinterpret_cast<float4*>(&out[(size_t)n * HC + head * CDIM + l16 * 4]) = o;
        }
    } else {  // streaming fallback (not hit for this graph; correctness-safe)
        float m = -1e30f;
        for (int j = start + lane; j < start + deg; j += 64) {
            float a = al_src[csr_src[j] * 3 + head] + ad;
            a = a > 0.f ? a : 0.2f * a;
            m = fmaxf(m, a);
        }
#pragma unroll
        for (int off = 32; off; off >>= 1) m = fmaxf(m, __shfl_xor(m, off));
        float acc = 0.f, ssum = 0.f;
        for (int j = start; j < start + deg; ++j) {
            int s = csr_src[j];
            float a = al_src[s * 3 + head] + ad;
            a = a > 0.f ? a : 0.2f * a;
            float w = __expf(a - m);
            ssum += w;
            acc = fmaf(w, __half2float(h[(size_t)s * HC + head * CDIM + lane]), acc);
        }
        float o = acc / (ssum + 1e-16f) + bias[head * CDIM + lane];
        out[(size_t)n * HC + head * CDIM + lane] = fmaxf(o, 0.f);
    }
}

// ---------------------------------------------------------------------------
// mu/lv aggregation fused: 3 waves/node; each wave = one head, BOTH mu & lv.
// Doubles loads-in-flight per wave, doubles resident blocks (192 thr).
// ---------------------------------------------------------------------------
__global__ __launch_bounds__(192) void agg_mean2_kernel(const int* __restrict__ row_ptr,
                                                        const int* __restrict__ csr_src,
                                                        const __half* __restrict__ h_mu,
                                                        const __half* __restrict__ h_lv,
                                                        const float* __restrict__ alms,
                                                        const float* __restrict__ almd,
                                                        const float* __restrict__ alls,
                                                        const float* __restrict__ alld,
                                                        const float* __restrict__ b_mu,
                                                        const float* __restrict__ b_lv,
                                                        float* __restrict__ out) {
    __shared__ int slds3[MAXDEG];
    __shared__ int sldsHC[MAXDEG];
    __shared__ float wm_[3][MAXDEG], wl_[3][MAXDEG];
    __shared__ __align__(16) float red[6][64];
    int n = blockIdx.x;
    int head = threadIdx.x >> 6;   // 0..2
    int lane = threadIdx.x & 63;
    int start = row_ptr[n];
    int deg = row_ptr[n + 1] - start;
    float adm = almd[n * 3 + head];
    float adl = alld[n * 3 + head];

    if (deg <= MAXDEG) {
        if (threadIdx.x < deg) {
            int s = csr_src[start + threadIdx.x];
            slds3[threadIdx.x] = s * 3;
            sldsHC[threadIdx.x] = s * HC;
        }
        __syncthreads();
        // ---- softmax weights for mu and lv, interleaved (2x MLP) ----
        float mm = -1e30f, ml = -1e30f;
        for (int j = lane; j < deg; j += 64) {
            int idx = slds3[j] + head;
            float am = alms[idx] + adm;
            float av = alls[idx] + adl;
            am = am > 0.f ? am : 0.2f * am;
            av = av > 0.f ? av : 0.2f * av;
            wm_[head][j] = am; wl_[head][j] = av;
            mm = fmaxf(mm, am); ml = fmaxf(ml, av);
        }
#pragma unroll
        for (int off = 32; off; off >>= 1) {
            mm = fmaxf(mm, __shfl_xor(mm, off));
            ml = fmaxf(ml, __shfl_xor(ml, off));
        }
        float sm = 0.f, sl = 0.f;
        for (int j = lane; j < deg; j += 64) {
            float em = __expf(wm_[head][j] - mm); wm_[head][j] = em; sm += em;
            float el = __expf(wl_[head][j] - ml); wl_[head][j] = el; sl += el;
        }
#pragma unroll
        for (int off = 32; off; off >>= 1) {
            sm += __shfl_xor(sm, off);
            sl += __shfl_xor(sl, off);
        }
        // ---- joint gather: 4 loads in flight per iteration ----
        const int sub = lane >> 4, l16 = lane & 15;
        const int hoff = head * CDIM + l16 * 4;
        float4 am4 = make_float4(0.f, 0.f, 0.f, 0.f);
        float4 al4 = make_float4(0.f, 0.f, 0.f, 0.f);
        int j = 0;
        for (; j + 8 <= deg; j += 8) {
            int sA = sldsHC[j + sub], sB = sldsHC[j + 4 + sub];
            float wmA = wm_[head][j + sub], wmB = wm_[head][j + 4 + sub];
            float wlA = wl_[head][j + sub], wlB = wl_[head][j + 4 + sub];
            uint2 uMA = *reinterpret_cast<const uint2*>(&h_mu[sA + hoff]);
            uint2 uLA = *reinterpret_cast<const uint2*>(&h_lv[sA + hoff]);
            uint2 uMB = *reinterpret_cast<const uint2*>(&h_mu[sB + hoff]);
            uint2 uLB = *reinterpret_cast<const uint2*>(&h_lv[sB + hoff]);
            am4 = fma4h(wmA, uMA, am4); al4 = fma4h(wlA, uLA, al4);
            am4 = fma4h(wmB, uMB, am4); al4 = fma4h(wlB, uLB, al4);
        }
        if (j + 4 <= deg) {
            int s = sldsHC[j + sub];
            float wmA = wm_[head][j + sub], wlA = wl_[head][j + sub];
            uint2 uM = *reinterpret_cast<const uint2*>(&h_mu[s + hoff]);
            uint2 uL = *reinterpret_cast<const uint2*>(&h_lv[s + hoff]);
            am4 = fma4h(wmA, uM, am4); al4 = fma4h(wlA, uL, al4);
            j += 4;
        }
        int rem = deg - j;
        if (sub < rem) {
            int s = sldsHC[j + sub];
            float wmA = wm_[head][j + sub], wlA = wl_[head][j + sub];
            uint2 uM = *reinterpret_cast<const uint2*>(&h_mu[s + hoff]);
            uint2 uL = *reinterpret_cast<const uint2*>(&h_lv[s + hoff]);
            am4 = fma4h(wmA, uM, am4); al4 = fma4h(wlA, uL, al4);
        }
#pragma unroll
        for (int off = 16; off <= 32; off <<= 1) {
            am4.x += __shfl_xor(am4.x, off); am4.y += __shfl_xor(am4.y, off);
            am4.z += __shfl_xor(am4.z, off); am4.w += __shfl_xor(am4.w, off);
            al4.x += __shfl_xor(al4.x, off); al4.y += __shfl_xor(al4.y, off);
            al4.z += __shfl_xor(al4.z, off); al4.w += __shfl_xor(al4.w, off);
        }
        if (lane < 16) {
            float invm = 1.f / (sm + 1e-16f);
            float invl = 1.f / (sl + 1e-16f);
            float4 rm, rl;
            rm.x = am4.x * invm; rm.y = am4.y * invm; rm.z = am4.z * invm; rm.w = am4.w * invm;
            rl.x = al4.x * invl; rl.y = al4.y * invl; rl.z = al4.z * invl; rl.w = al4.w * invl;
            *reinterpret_cast<float4*>(&red[head][l16 * 4]) = rm;
            *reinterpret_cast<float4*>(&red[3 + head][l16 * 4]) = rl;
        }
    } else {  // streaming fallback (not hit; correctness-safe)
        for (int pass = 0; pass < 2; ++pass) {
            const __half* h = pass ? h_lv : h_mu;
            const float* as = pass ? alls : alms;
            float ad = pass ? adl : adm;
            float m = -1e30f;
            for (int j = start + lane; j < start + deg; j += 64) {
                float a = as[csr_src[j] * 3 + head] + ad;
                a = a > 0.f ? a : 0.2f * a;
                m = fmaxf(m, a);
            }
#pragma unroll
            for (int off = 32; off; off >>= 1) m = fmaxf(m, __shfl_xor(m, off));
            float acc = 0.f, ssum = 0.f;
            for (int j = start; j < start + deg; ++j) {
                int s = csr_src[j];
                float a = as[s * 3 + head] + ad;
                a = a > 0.f ? a : 0.2f * a;
                float w = __expf(a - m);
                ssum += w;
                acc = fmaf(w, __half2float(h[(size_t)s * HC + head * CDIM + lane]), acc);
            }
            red[pass * 3 + head][lane] = acc / (ssum + 1e-16f);
        }
    }
    __syncthreads();
    if (threadIdx.x < 64) {
        out[(size_t)n * CDIM + lane] =
            (red[0][lane] + red[1][lane] + red[2][lane]) * (1.f / 3.f) + b_mu[lane];
    } else if (threadIdx.x < 128) {
        out[(size_t)NN * CDIM + (size_t)n * CDIM + lane] =
            (red[3][lane] + red[4][lane] + red[5][lane]) * (1.f / 3.f) + b_lv[lane];
    }
}

// ---------------------------------------------------------------------------
extern "C" void kernel_launch(void* const* d_in, const int* in_sizes, int n_in,
                              void* d_out, int out_size, void* d_ws, size_t ws_size,
                              hipStream_t stream) {
    const float* x    = (const float*)d_in[0];
    const int*   ei   = (const int*)d_in[1];
    const float* W1   = (const float*)d_in[2];
    const float* a1s  = (const float*)d_in[3];
    const float* a1d  = (const float*)d_in[4];
    const float* b1   = (const float*)d_in[5];
    const float* Wmu  = (const float*)d_in[6];
    const float* amus = (const float*)d_in[7];
    const float* amud = (const float*)d_in[8];
    const float* bmu  = (const float*)d_in[9];
    const float* Wlv  = (const float*)d_in[10];
    const float* alvs = (const float*)d_in[11];
    const float* alvd = (const float*)d_in[12];
    const float* blv  = (const float*)d_in[13];
    float* out = (float*)d_out;

    // workspace carve (256B aligned)
    size_t off = 0;
    auto carve = [&](size_t bytes) {
        void* p = (char*)d_ws + off;
        off += (bytes + 255) & ~(size_t)255;
        return p;
    };
    int*    cnt      = (int*)carve((size_t)NN * 4);
    int*    row_ptr  = (int*)carve((size_t)(NN + 1) * 4);
    int*    partials = (int*)carve(64 * 4);
    int*    csr      = (int*)carve((size_t)ET * 4);
    __half* h1f16    = (__half*)carve((size_t)NN * HC * 2);
    float*  hrelu    = (float*)carve((size_t)NN * HC * 4);
    __half* hmu16    = (__half*)carve((size_t)NN * HC * 2);
    __half* hlv16    = (__half*)carve((size_t)NN * HC * 2);
    float*  al1s     = (float*)carve((size_t)NN * 3 * 4);
    float*  al1d     = (float*)carve((size_t)NN * 3 * 4);
    float*  alms     = (float*)carve((size_t)NN * 3 * 4);
    float*  almd     = (float*)carve((size_t)NN * 3 * 4);
    float*  alls     = (float*)carve((size_t)NN * 3 * 4);
    float*  alld     = (float*)carve((size_t)NN * 3 * 4);

    const int scan_blocks = (NN + SCAN_BLK - 1) / SCAN_BLK;  // 49

    // ---- CSR build (shared by all 3 layers) ----
    hipMemsetAsync(cnt, 0, (size_t)NN * 4, stream);
    hist_kernel<<<(ET + 255) / 256, 256, 0, stream>>>(ei, cnt);
    scan1_kernel<<<scan_blocks, SCAN_BLK, 0, stream>>>(cnt, row_ptr, partials);
    scan2_kernel<<<1, 64, 0, stream>>>(partials, scan_blocks);
    scan3_kernel<<<scan_blocks, SCAN_BLK, 0, stream>>>(row_ptr, partials);
    hipMemsetAsync(cnt, 0, (size_t)NN * 4, stream);
    scatter_kernel<<<(ET + 255) / 256, 256, 0, stream>>>(ei, cnt, row_ptr, csr);

    // ---- Layer 1 (fp16 h) ----
    dim3 g1((NN + 127) / 128, HC / 64);
    sgemm_mfma<__half><<<g1, 256, 0, stream>>>(x, W1, h1f16, NN, HC, FIN);
    al_h_kernel<<<(NN * 3 + 3) / 4, 256, 0, stream>>>(h1f16, a1s, a1d, al1s, al1d);
    agg_cat_kernel<<<NN, 192, 0, stream>>>(row_ptr, csr, h1f16, al1s, al1d, b1, hrelu);

    // ---- Layers mu / lv (fp16 h) ----
    sgemm_mfma<__half><<<g1, 256, 0, stream>>>(hrelu, Wmu, hmu16, NN, HC, HC);
    sgemm_mfma<__half><<<g1, 256, 0, stream>>>(hrelu, Wlv, hlv16, NN, HC, HC);
    al_h_kernel<<<(NN * 3 + 3) / 4, 256, 0, stream>>>(hmu16, amus, amud, alms, almd);
    al_h_kernel<<<(NN * 3 + 3) / 4, 256, 0, stream>>>(hlv16, alvs, alvd, alls, alld);
    agg_mean2_kernel<<<NN, 192, 0, stream>>>(row_ptr, csr, hmu16, hlv16,
                                             alms, almd, alls, alld, bmu, blv, out);
}

// Round 7
// 532.403 us; speedup vs baseline: 1.9300x; 1.0286x over previous
//
#include <hip/hip_runtime.h>
#include <hip/hip_bf16.h>
#include <hip/hip_fp16.h>

// Problem constants (from reference)
#define NN 50000
#define NE 800000
#define ET (NE + NN)          // edges + self loops = 850000
#define FIN 256
#define HC 192                // H*C = 3*64
#define NHEAD 3
#define CDIM 64
#define MAXDEG 128            // fast-path cap; Poisson(17) max over 50K nodes ~45
#define MLW 384               // hml row width (mu 0..191 | lv 192..383)

typedef short short8 __attribute__((ext_vector_type(8)));
typedef float f32x4 __attribute__((ext_vector_type(4)));

// ---------------------------------------------------------------------------
// CSR build: histogram -> scan -> scatter (graph shared by all 3 GAT layers)
// ---------------------------------------------------------------------------
__global__ __launch_bounds__(256) void hist_kernel(const int* __restrict__ ei,
                                                   int* __restrict__ cnt) {
    int e = blockIdx.x * 256 + threadIdx.x;
    if (e >= ET) return;
    int dst = (e < NE) ? ei[NE + e] : (e - NE);
    atomicAdd(&cnt[dst], 1);
}

#define SCAN_BLK 1024
__global__ __launch_bounds__(SCAN_BLK) void scan1_kernel(const int* __restrict__ cnt,
                                                         int* __restrict__ row_ptr,
                                                         int* __restrict__ partials) {
    __shared__ int sm[SCAN_BLK];
    int t = threadIdx.x;
    int g = blockIdx.x * SCAN_BLK + t;
    int v = (g < NN) ? cnt[g] : 0;
    sm[t] = v;
    __syncthreads();
    for (int off = 1; off < SCAN_BLK; off <<= 1) {
        int u = (t >= off) ? sm[t - off] : 0;
        __syncthreads();
        sm[t] += u;
        __syncthreads();
    }
    if (g < NN) row_ptr[g + 1] = sm[t];
    if (t == SCAN_BLK - 1) partials[blockIdx.x] = sm[t];
}

__global__ __launch_bounds__(64) void scan2_kernel(int* __restrict__ partials, int nb) {
    int t = threadIdx.x;
    int v = (t < nb) ? partials[t] : 0;
    int x = v;
    for (int off = 1; off < 64; off <<= 1) {
        int y = __shfl_up(x, off);
        if (t >= off) x += y;
    }
    if (t < nb) partials[t] = x - v;
}

// also zeroes cnt so scatter can reuse it (saves a memset dispatch)
__global__ __launch_bounds__(SCAN_BLK) void scan3_kernel(int* __restrict__ row_ptr,
                                                         const int* __restrict__ partials,
                                                         int* __restrict__ cnt) {
    int g = blockIdx.x * SCAN_BLK + threadIdx.x;
    if (g < NN) {
        row_ptr[g + 1] += partials[blockIdx.x];
        cnt[g] = 0;
    }
    if (g == 0) row_ptr[0] = 0;
}

__global__ __launch_bounds__(256) void scatter_kernel(const int* __restrict__ ei,
                                                      int* __restrict__ cnt,
                                                      const int* __restrict__ row_ptr,
                                                      int* __restrict__ csr_src) {
    int e = blockIdx.x * 256 + threadIdx.x;
    if (e >= ET) return;
    int src, dst;
    if (e < NE) { src = ei[e]; dst = ei[NE + e]; }
    else        { src = e - NE; dst = e - NE; }
    int pos = atomicAdd(&cnt[dst], 1);
    csr_src[row_ptr[dst] + pos] = src;
}

// ---------------------------------------------------------------------------
// fp32 -> bf16 split helpers
// ---------------------------------------------------------------------------
__device__ __forceinline__ unsigned short f2bf(float f) {
    unsigned int u = __float_as_uint(f);
    unsigned int r = (u + 0x7FFFu + ((u >> 16) & 1u)) >> 16;   // RNE
    return (unsigned short)r;
}
__device__ __forceinline__ float bf2f(unsigned short h) {
    return __uint_as_float(((unsigned int)h) << 16);
}

// ---------------------------------------------------------------------------
// Split-bf16 MFMA GEMM: C[M,N] = A[M,K] * B[N,K]^T (fp32 in, ~fp32 acc).
// BM=128, BN=64, BK=32; 256 threads = 4 waves (2x2), wave tile 64x32.
// Output fp16, optional output row stride / dual-B (for fused mu|lv GEMM).
// ---------------------------------------------------------------------------
#define LSTR 40
__device__ __forceinline__ void gemm_core(const float* __restrict__ A,
                                          const float* __restrict__ B1,
                                          const float* __restrict__ B2,
                                          __half* __restrict__ C,
                                          int M, int CS, int K) {
    __shared__ unsigned short Ah[128 * LSTR], Al[128 * LSTR];
    __shared__ unsigned short Bh[64 * LSTR],  Bl[64 * LSTR];

    const int tid  = threadIdx.x;
    const int lane = tid & 63;
    const int wid  = tid >> 6;
    const int wm   = wid & 1;
    const int wn   = wid >> 1;
    const int quad = lane >> 4;
    const int l15  = lane & 15;
    const int m0   = blockIdx.x * 128;
    const int n0   = blockIdx.y * 64;

    const int srow = tid >> 3;       // 0..31
    const int scol = (tid & 7) * 4;  // float offset

    f32x4 acc[4][2];
#pragma unroll
    for (int i = 0; i < 4; i++)
#pragma unroll
        for (int j = 0; j < 2; j++) acc[i][j] = (f32x4)(0.f);

    for (int k0 = 0; k0 < K; k0 += 32) {
#pragma unroll
        for (int p = 0; p < 4; p++) {
            int r = srow + p * 32;
            int gm = m0 + r;
            float4 v = make_float4(0.f, 0.f, 0.f, 0.f);
            if (gm < M) v = *reinterpret_cast<const float4*>(&A[(size_t)gm * K + k0 + scol]);
            unsigned short h0 = f2bf(v.x), h1 = f2bf(v.y), h2 = f2bf(v.z), h3 = f2bf(v.w);
            unsigned short g0 = f2bf(v.x - bf2f(h0)), g1 = f2bf(v.y - bf2f(h1));
            unsigned short g2 = f2bf(v.z - bf2f(h2)), g3 = f2bf(v.w - bf2f(h3));
            int off = r * LSTR + scol;
            *reinterpret_cast<uint2*>(&Ah[off]) =
                make_uint2((unsigned)h0 | ((unsigned)h1 << 16), (unsigned)h2 | ((unsigned)h3 << 16));
            *reinterpret_cast<uint2*>(&Al[off]) =
                make_uint2((unsigned)g0 | ((unsigned)g1 << 16), (unsigned)g2 | ((unsigned)g3 << 16));
        }
#pragma unroll
        for (int p = 0; p < 2; p++) {
            int r = srow + p * 32;
            int r2 = n0 + r;
            const float* Brow = (r2 < 192) ? &B1[(size_t)r2 * K] : &B2[(size_t)(r2 - 192) * K];
            float4 v = *reinterpret_cast<const float4*>(&Brow[k0 + scol]);
            unsigned short h0 = f2bf(v.x), h1 = f2bf(v.y), h2 = f2bf(v.z), h3 = f2bf(v.w);
            unsigned short g0 = f2bf(v.x - bf2f(h0)), g1 = f2bf(v.y - bf2f(h1));
            unsigned short g2 = f2bf(v.z - bf2f(h2)), g3 = f2bf(v.w - bf2f(h3));
            int off = r * LSTR + scol;
            *reinterpret_cast<uint2*>(&Bh[off]) =
                make_uint2((unsigned)h0 | ((unsigned)h1 << 16), (unsigned)h2 | ((unsigned)h3 << 16));
            *reinterpret_cast<uint2*>(&Bl[off]) =
                make_uint2((unsigned)g0 | ((unsigned)g1 << 16), (unsigned)g2 | ((unsigned)g3 << 16));
        }
        __syncthreads();

        short8 afh[4], afl[4], bfh[2], bfl[2];
#pragma unroll
        for (int tm = 0; tm < 4; tm++) {
            int off = (wm * 64 + tm * 16 + l15) * LSTR + quad * 8;
            afh[tm] = *reinterpret_cast<const short8*>(&Ah[off]);
            afl[tm] = *reinterpret_cast<const short8*>(&Al[off]);
        }
#pragma unroll
        for (int tn = 0; tn < 2; tn++) {
            int off = (wn * 32 + tn * 16 + l15) * LSTR + quad * 8;
            bfh[tn] = *reinterpret_cast<const short8*>(&Bh[off]);
            bfl[tn] = *reinterpret_cast<const short8*>(&Bl[off]);
        }
#pragma unroll
        for (int tm = 0; tm < 4; tm++)
#pragma unroll
            for (int tn = 0; tn < 2; tn++) {
                acc[tm][tn] = __builtin_amdgcn_mfma_f32_16x16x32_bf16(afh[tm], bfh[tn], acc[tm][tn], 0, 0, 0);
                acc[tm][tn] = __builtin_amdgcn_mfma_f32_16x16x32_bf16(afh[tm], bfl[tn], acc[tm][tn], 0, 0, 0);
                acc[tm][tn] = __builtin_amdgcn_mfma_f32_16x16x32_bf16(afl[tm], bfh[tn], acc[tm][tn], 0, 0, 0);
            }
        __syncthreads();
    }

#pragma unroll
    for (int tm = 0; tm < 4; tm++) {
        int rbase = m0 + wm * 64 + tm * 16 + quad * 4;
#pragma unroll
        for (int r = 0; r < 4; r++) {
            int row = rbase + r;
            if (row < M) {
#pragma unroll
                for (int tn = 0; tn < 2; tn++) {
                    int col = n0 + wn * 32 + tn * 16 + l15;
                    C[(size_t)row * CS + col] = __float2half(acc[tm][tn][r]);
                }
            }
        }
    }
}

__global__ __launch_bounds__(256) void sgemm1(const float* __restrict__ A,
                                              const float* __restrict__ B,
                                              __half* __restrict__ C) {
    gemm_core(A, B, B, C, NN, HC, FIN);      // N=192, B2 never selected
}

__global__ __launch_bounds__(256) void sgemm23(const float* __restrict__ A,
                                               const float* __restrict__ Bmu,
                                               const float* __restrict__ Blv,
                                               __half* __restrict__ C) {
    gemm_core(A, Bmu, Blv, C, NN, MLW, HC);  // N=384 = mu|lv
}

// ---------------------------------------------------------------------------
// Attention logits, layer 1 (h stride HC)
// ---------------------------------------------------------------------------
__global__ __launch_bounds__(256) void al_h_kernel(const __half* __restrict__ h,
                                                   const float* __restrict__ a_src,
                                                   const float* __restrict__ a_dst,
                                                   float* __restrict__ al_src,
                                                   float* __restrict__ al_dst) {
    int wid = (blockIdx.x * 256 + threadIdx.x) >> 6;
    int lane = threadIdx.x & 63;
    if (wid >= NN * NHEAD) return;
    int n = wid / 3;
    int head = wid - n * 3;
    float v = __half2float(h[(size_t)n * HC + head * CDIM + lane]);
    float ps = v * a_src[head * CDIM + lane];
    float pd = v * a_dst[head * CDIM + lane];
#pragma unroll
    for (int off = 32; off; off >>= 1) {
        ps += __shfl_xor(ps, off);
        pd += __shfl_xor(pd, off);
    }
    if (lane == 0) { al_src[wid] = ps; al_dst[wid] = pd; }
}

// Fused mu+lv logits from hml (stride MLW): 4 outputs in one pass.
__global__ __launch_bounds__(256) void al_ml_kernel(const __half* __restrict__ hml,
                                                    const float* __restrict__ amus,
                                                    const float* __restrict__ amud,
                                                    const float* __restrict__ alvs,
                                                    const float* __restrict__ alvd,
                                                    float* __restrict__ alms,
                                                    float* __restrict__ almd,
                                                    float* __restrict__ alls,
                                                    float* __restrict__ alld) {
    int wid = (blockIdx.x * 256 + threadIdx.x) >> 6;
    int lane = threadIdx.x & 63;
    if (wid >= NN * NHEAD) return;
    int n = wid / 3;
    int head = wid - n * 3;
    int c = head * CDIM + lane;
    float vm = __half2float(hml[(size_t)n * MLW + c]);
    float vl = __half2float(hml[(size_t)n * MLW + 192 + c]);
    float ms = vm * amus[c], md = vm * amud[c];
    float ls = vl * alvs[c], ld = vl * alvd[c];
#pragma unroll
    for (int off = 32; off; off >>= 1) {
        ms += __shfl_xor(ms, off);
        md += __shfl_xor(md, off);
        ls += __shfl_xor(ls, off);
        ld += __shfl_xor(ld, off);
    }
    if (lane == 0) { alms[wid] = ms; almd[wid] = md; alls[wid] = ls; alld[wid] = ld; }
}

// ---------------------------------------------------------------------------
// Per-wave softmax weights into LDS; returns softmax denominator.
// ---------------------------------------------------------------------------
__device__ __forceinline__ float edge_weights(const int* slds3, float* wrow,
                                              const float* __restrict__ al_s,
                                              float ad, int head, int deg, int lane) {
    float m = -1e30f;
    for (int j = lane; j < deg; j += 64) {
        float a = al_s[slds3[j] + head] + ad;
        a = a > 0.f ? a : 0.2f * a;
        wrow[j] = a;
        m = fmaxf(m, a);
    }
#pragma unroll
    for (int off = 32; off; off >>= 1) m = fmaxf(m, __shfl_xor(m, off));
    float ssum = 0.f;
    for (int j = lane; j < deg; j += 64) {
        float w = __expf(wrow[j] - m);
        wrow[j] = w;
        ssum += w;
    }
#pragma unroll
    for (int off = 32; off; off >>= 1) ssum += __shfl_xor(ssum, off);
    return ssum;
}

__device__ __forceinline__ float4 fma4h(float w, uint2 u, float4 acc) {
    __half2 p0 = *reinterpret_cast<__half2*>(&u.x);
    __half2 p1 = *reinterpret_cast<__half2*>(&u.y);
    float2 f0 = __half22float2(p0);
    float2 f1 = __half22float2(p1);
    acc.x = fmaf(w, f0.x, acc.x); acc.y = fmaf(w, f0.y, acc.y);
    acc.z = fmaf(w, f1.x, acc.z); acc.w = fmaf(w, f1.y, acc.w);
    return acc;
}

// ---------------------------------------------------------------------------
// Layer-1 aggregation (concat + bias + relu). 3 waves/node, fp16 h.
// 16 edges/iter: 4 independent gather loads in flight.
// ---------------------------------------------------------------------------
__global__ __launch_bounds__(192) void agg_cat_kernel(const int* __restrict__ row_ptr,
                                                      const int* __restrict__ csr_src,
                                                      const __half* __restrict__ h,
                                                      const float* __restrict__ al_src,
                                                      const float* __restrict__ al_dst,
                                                      const float* __restrict__ bias,
                                                      float* __restrict__ out) {
    __shared__ int slds3[MAXDEG];
    __shared__ int sldsHC[MAXDEG];
    __shared__ float wlds[3][MAXDEG];
    int n = blockIdx.x;
    int head = threadIdx.x >> 6;
    int lane = threadIdx.x & 63;
    int start = row_ptr[n];
    int deg = row_ptr[n + 1] - start;
    float ad = al_dst[n * 3 + head];

    if (deg <= MAXDEG) {
        if (threadIdx.x < deg) {
            int s = csr_src[start + threadIdx.x];
            slds3[threadIdx.x] = s * 3;
            sldsHC[threadIdx.x] = s * HC;
        }
        __syncthreads();
        float ssum = edge_weights(slds3, wlds[head], al_src, ad, head, deg, lane);
        const int sub = lane >> 4, l16 = lane & 15;
        const int hoff = head * CDIM + l16 * 4;
        const float* wrow = wlds[head];
        float4 acc = make_float4(0.f, 0.f, 0.f, 0.f);
        int j = 0;
        for (; j + 16 <= deg; j += 16) {
            int s0 = sldsHC[j + sub],      s1 = sldsHC[j + 4 + sub];
            int s2 = sldsHC[j + 8 + sub],  s3 = sldsHC[j + 12 + sub];
            float w0 = wrow[j + sub],      w1 = wrow[j + 4 + sub];
            float w2 = wrow[j + 8 + sub],  w3 = wrow[j + 12 + sub];
            uint2 u0 = *reinterpret_cast<const uint2*>(&h[s0 + hoff]);
            uint2 u1 = *reinterpret_cast<const uint2*>(&h[s1 + hoff]);
            uint2 u2 = *reinterpret_cast<const uint2*>(&h[s2 + hoff]);
            uint2 u3 = *reinterpret_cast<const uint2*>(&h[s3 + hoff]);
            acc = fma4h(w0, u0, acc); acc = fma4h(w1, u1, acc);
            acc = fma4h(w2, u2, acc); acc = fma4h(w3, u3, acc);
        }
        for (; j + 4 <= deg; j += 4) {
            int s = sldsHC[j + sub];
            float w = wrow[j + sub];
            uint2 u = *reinterpret_cast<const uint2*>(&h[s + hoff]);
            acc = fma4h(w, u, acc);
        }
        if (sub < deg - j) {
            int s = sldsHC[j + sub];
            float w = wrow[j + sub];
            uint2 u = *reinterpret_cast<const uint2*>(&h[s + hoff]);
            acc = fma4h(w, u, acc);
        }
#pragma unroll
        for (int off = 16; off <= 32; off <<= 1) {
            acc.x += __shfl_xor(acc.x, off);
            acc.y += __shfl_xor(acc.y, off);
            acc.z += __shfl_xor(acc.z, off);
            acc.w += __shfl_xor(acc.w, off);
        }
        if (lane < 16) {
            float inv = 1.f / (ssum + 1e-16f);
            const float4 b4 = *reinterpret_cast<const float4*>(&bias[head * CDIM + l16 * 4]);
            float4 o;
            o.x = fmaxf(fmaf(acc.x, inv, b4.x), 0.f);
            o.y = fmaxf(fmaf(acc.y, inv, b4.y), 0.f);
            o.z = fmaxf(fmaf(acc.z, inv, b4.z), 0.f);
            o.w = fmaxf(fmaf(acc.w, inv, b4.w), 0.f);
            *reinterpret_cast<float4*>(&out[(size_t)n * HC + head * CDIM + l16 * 4]) = o;
        }
    } else {  // streaming fallback (not hit for this graph; correctness-safe)
        float m = -1e30f;
        for (int j = start + lane; j < start + deg; j += 64) {
            float a = al_src[csr_src[j] * 3 + head] + ad;
            a = a > 0.f ? a : 0.2f * a;
            m = fmaxf(m, a);
        }
#pragma unroll
        for (int off = 32; off; off >>= 1) m = fmaxf(m, __shfl_xor(m, off));
        float acc = 0.f, ssum = 0.f;
        for (int j = start; j < start + deg; ++j) {
            int s = csr_src[j];
            float a = al_src[s * 3 + head] + ad;
            a = a > 0.f ? a : 0.2f * a;
            float w = __expf(a - m);
            ssum += w;
            acc = fmaf(w, __half2float(h[(size_t)s * HC + head * CDIM + lane]), acc);
        }
        float o = acc / (ssum + 1e-16f) + bias[head * CDIM + lane];
        out[(size_t)n * HC + head * CDIM + lane] = fmaxf(o, 0.f);
    }
}

// ---------------------------------------------------------------------------
// mu/lv aggregation fused over interleaved hml[n][384]: 3 waves/node, each
// wave = one head, both mu & lv; 16 edges/iter -> 8 loads in flight.
// ---------------------------------------------------------------------------
__global__ __launch_bounds__(192) void agg_mean2_kernel(const int* __restrict__ row_ptr,
                                                        const int* __restrict__ csr_src,
                                                        const __half* __restrict__ hml,
                                                        const float* __restrict__ alms,
                                                        const float* __restrict__ almd,
                                                        const float* __restrict__ alls,
                                                        const float* __restrict__ alld,
                                                        const float* __restrict__ b_mu,
                                                        const float* __restrict__ b_lv,
                                                        float* __restrict__ out) {
    __shared__ int slds3[MAXDEG];
    __shared__ int sldsML[MAXDEG];
    __shared__ float wm_[3][MAXDEG], wl_[3][MAXDEG];
    __shared__ __align__(16) float red[6][64];
    int n = blockIdx.x;
    int head = threadIdx.x >> 6;   // 0..2
    int lane = threadIdx.x & 63;
    int start = row_ptr[n];
    int deg = row_ptr[n + 1] - start;
    float adm = almd[n * 3 + head];
    float adl = alld[n * 3 + head];

    if (deg <= MAXDEG) {
        if (threadIdx.x < deg) {
            int s = csr_src[start + threadIdx.x];
            slds3[threadIdx.x] = s * 3;
            sldsML[threadIdx.x] = s * MLW;
        }
        __syncthreads();
        // softmax weights for mu and lv, interleaved
        float mm = -1e30f, ml = -1e30f;
        for (int j = lane; j < deg; j += 64) {
            int idx = slds3[j] + head;
            float am = alms[idx] + adm;
            float av = alls[idx] + adl;
            am = am > 0.f ? am : 0.2f * am;
            av = av > 0.f ? av : 0.2f * av;
            wm_[head][j] = am; wl_[head][j] = av;
            mm = fmaxf(mm, am); ml = fmaxf(ml, av);
        }
#pragma unroll
        for (int off = 32; off; off >>= 1) {
            mm = fmaxf(mm, __shfl_xor(mm, off));
            ml = fmaxf(ml, __shfl_xor(ml, off));
        }
        float sm = 0.f, sl = 0.f;
        for (int j = lane; j < deg; j += 64) {
            float em = __expf(wm_[head][j] - mm); wm_[head][j] = em; sm += em;
            float el = __expf(wl_[head][j] - ml); wl_[head][j] = el; sl += el;
        }
#pragma unroll
        for (int off = 32; off; off >>= 1) {
            sm += __shfl_xor(sm, off);
            sl += __shfl_xor(sl, off);
        }
        // joint gather: 8 loads in flight per iteration
        const int sub = lane >> 4, l16 = lane & 15;
        const int hoffm = head * CDIM + l16 * 4;
        const int hoffl = hoffm + 192;
        float4 am4 = make_float4(0.f, 0.f, 0.f, 0.f);
        float4 al4 = make_float4(0.f, 0.f, 0.f, 0.f);
        int j = 0;
        for (; j + 16 <= deg; j += 16) {
            int s0 = sldsML[j + sub],     s1 = sldsML[j + 4 + sub];
            int s2 = sldsML[j + 8 + sub], s3 = sldsML[j + 12 + sub];
            float wm0 = wm_[head][j + sub],      wm1 = wm_[head][j + 4 + sub];
            float wm2 = wm_[head][j + 8 + sub],  wm3 = wm_[head][j + 12 + sub];
            float wl0 = wl_[head][j + sub],      wl1 = wl_[head][j + 4 + sub];
            float wl2 = wl_[head][j + 8 + sub],  wl3 = wl_[head][j + 12 + sub];
            uint2 uM0 = *reinterpret_cast<const uint2*>(&hml[s0 + hoffm]);
            uint2 uL0 = *reinterpret_cast<const uint2*>(&hml[s0 + hoffl]);
            uint2 uM1 = *reinterpret_cast<const uint2*>(&hml[s1 + hoffm]);
            uint2 uL1 = *reinterpret_cast<const uint2*>(&hml[s1 + hoffl]);
            uint2 uM2 = *reinterpret_cast<const uint2*>(&hml[s2 + hoffm]);
            uint2 uL2 = *reinterpret_cast<const uint2*>(&hml[s2 + hoffl]);
            uint2 uM3 = *reinterpret_cast<const uint2*>(&hml[s3 + hoffm]);
            uint2 uL3 = *reinterpret_cast<const uint2*>(&hml[s3 + hoffl]);
            am4 = fma4h(wm0, uM0, am4); al4 = fma4h(wl0, uL0, al4);
            am4 = fma4h(wm1, uM1, am4); al4 = fma4h(wl1, uL1, al4);
            am4 = fma4h(wm2, uM2, am4); al4 = fma4h(wl2, uL2, al4);
            am4 = fma4h(wm3, uM3, am4); al4 = fma4h(wl3, uL3, al4);
        }
        for (; j + 4 <= deg; j += 4) {
            int s = sldsML[j + sub];
            float wmA = wm_[head][j + sub], wlA = wl_[head][j + sub];
            uint2 uM = *reinterpret_cast<const uint2*>(&hml[s + hoffm]);
            uint2 uL = *reinterpret_cast<const uint2*>(&hml[s + hoffl]);
            am4 = fma4h(wmA, uM, am4); al4 = fma4h(wlA, uL, al4);
        }
        if (sub < deg - j) {
            int s = sldsML[j + sub];
            float wmA = wm_[head][j + sub], wlA = wl_[head][j + sub];
            uint2 uM = *reinterpret_cast<const uint2*>(&hml[s + hoffm]);
            uint2 uL = *reinterpret_cast<const uint2*>(&hml[s + hoffl]);
            am4 = fma4h(wmA, uM, am4); al4 = fma4h(wlA, uL, al4);
        }
#pragma unroll
        for (int off = 16; off <= 32; off <<= 1) {
            am4.x += __shfl_xor(am4.x, off); am4.y += __shfl_xor(am4.y, off);
            am4.z += __shfl_xor(am4.z, off); am4.w += __shfl_xor(am4.w, off);
            al4.x += __shfl_xor(al4.x, off); al4.y += __shfl_xor(al4.y, off);
            al4.z += __shfl_xor(al4.z, off); al4.w += __shfl_xor(al4.w, off);
        }
        if (lane < 16) {
            float invm = 1.f / (sm + 1e-16f);
            float invl = 1.f / (sl + 1e-16f);
            float4 rm, rl;
            rm.x = am4.x * invm; rm.y = am4.y * invm; rm.z = am4.z * invm; rm.w = am4.w * invm;
            rl.x = al4.x * invl; rl.y = al4.y * invl; rl.z = al4.z * invl; rl.w = al4.w * invl;
            *reinterpret_cast<float4*>(&red[head][l16 * 4]) = rm;
            *reinterpret_cast<float4*>(&red[3 + head][l16 * 4]) = rl;
        }
    } else {  // streaming fallback (not hit; correctness-safe)
        for (int pass = 0; pass < 2; ++pass) {
            const float* as = pass ? alls : alms;
            float ad = pass ? adl : adm;
            int coff = pass ? 192 : 0;
            float m = -1e30f;
            for (int j = start + lane; j < start + deg; j += 64) {
                float a = as[csr_src[j] * 3 + head] + ad;
                a = a > 0.f ? a : 0.2f * a;
                m = fmaxf(m, a);
            }
#pragma unroll
            for (int off = 32; off; off >>= 1) m = fmaxf(m, __shfl_xor(m, off));
            float acc = 0.f, ssum = 0.f;
            for (int j = start; j < start + deg; ++j) {
                int s = csr_src[j];
                float a = as[s * 3 + head] + ad;
                a = a > 0.f ? a : 0.2f * a;
                float w = __expf(a - m);
                ssum += w;
                acc = fmaf(w, __half2float(hml[(size_t)s * MLW + coff + head * CDIM + lane]), acc);
            }
            red[pass * 3 + head][lane] = acc / (ssum + 1e-16f);
        }
    }
    __syncthreads();
    if (threadIdx.x < 64) {
        out[(size_t)n * CDIM + lane] =
            (red[0][lane] + red[1][lane] + red[2][lane]) * (1.f / 3.f) + b_mu[lane];
    } else if (threadIdx.x < 128) {
        out[(size_t)NN * CDIM + (size_t)n * CDIM + lane] =
            (red[3][lane] + red[4][lane] + red[5][lane]) * (1.f / 3.f) + b_lv[lane];
    }
}

// ---------------------------------------------------------------------------
extern "C" void kernel_launch(void* const* d_in, const int* in_sizes, int n_in,
                              void* d_out, int out_size, void* d_ws, size_t ws_size,
                              hipStream_t stream) {
    const float* x    = (const float*)d_in[0];
    const int*   ei   = (const int*)d_in[1];
    const float* W1   = (const float*)d_in[2];
    const float* a1s  = (const float*)d_in[3];
    const float* a1d  = (const float*)d_in[4];
    const float* b1   = (const float*)d_in[5];
    const float* Wmu  = (const float*)d_in[6];
    const float* amus = (const float*)d_in[7];
    const float* amud = (const float*)d_in[8];
    const float* bmu  = (const float*)d_in[9];
    const float* Wlv  = (const float*)d_in[10];
    const float* alvs = (const float*)d_in[11];
    const float* alvd = (const float*)d_in[12];
    const float* blv  = (const float*)d_in[13];
    float* out = (float*)d_out;

    // workspace carve (256B aligned)
    size_t off = 0;
    auto carve = [&](size_t bytes) {
        void* p = (char*)d_ws + off;
        off += (bytes + 255) & ~(size_t)255;
        return p;
    };
    int*    cnt      = (int*)carve((size_t)NN * 4);
    int*    row_ptr  = (int*)carve((size_t)(NN + 1) * 4);
    int*    partials = (int*)carve(64 * 4);
    int*    csr      = (int*)carve((size_t)ET * 4);
    __half* h1f16    = (__half*)carve((size_t)NN * HC * 2);
    float*  hrelu    = (float*)carve((size_t)NN * HC * 4);
    __half* hml      = (__half*)carve((size_t)NN * MLW * 2);
    float*  al1s     = (float*)carve((size_t)NN * 3 * 4);
    float*  al1d     = (float*)carve((size_t)NN * 3 * 4);
    float*  alms     = (float*)carve((size_t)NN * 3 * 4);
    float*  almd     = (float*)carve((size_t)NN * 3 * 4);
    float*  alls     = (float*)carve((size_t)NN * 3 * 4);
    float*  alld     = (float*)carve((size_t)NN * 3 * 4);

    const int scan_blocks = (NN + SCAN_BLK - 1) / SCAN_BLK;  // 49

    // ---- CSR build (shared by all 3 layers) ----
    hipMemsetAsync(cnt, 0, (size_t)NN * 4, stream);
    hist_kernel<<<(ET + 255) / 256, 256, 0, stream>>>(ei, cnt);
    scan1_kernel<<<scan_blocks, SCAN_BLK, 0, stream>>>(cnt, row_ptr, partials);
    scan2_kernel<<<1, 64, 0, stream>>>(partials, scan_blocks);
    scan3_kernel<<<scan_blocks, SCAN_BLK, 0, stream>>>(row_ptr, partials, cnt);
    scatter_kernel<<<(ET + 255) / 256, 256, 0, stream>>>(ei, cnt, row_ptr, csr);

    // ---- Layer 1 (fp16 h) ----
    dim3 g1((NN + 127) / 128, HC / 64);
    sgemm1<<<g1, 256, 0, stream>>>(x, W1, h1f16);
    al_h_kernel<<<(NN * 3 + 3) / 4, 256, 0, stream>>>(h1f16, a1s, a1d, al1s, al1d);
    agg_cat_kernel<<<NN, 192, 0, stream>>>(row_ptr, csr, h1f16, al1s, al1d, b1, hrelu);

    // ---- Layers mu / lv fused: one GEMM (N=384), one al pass ----
    dim3 g2((NN + 127) / 128, MLW / 64);
    sgemm23<<<g2, 256, 0, stream>>>(hrelu, Wmu, Wlv, hml);
    al_ml_kernel<<<(NN * 3 + 3) / 4, 256, 0, stream>>>(hml, amus, amud, alvs, alvd,
                                                       alms, almd, alls, alld);
    agg_mean2_kernel<<<NN, 192, 0, stream>>>(row_ptr, csr, hml,
                                             alms, almd, alls, alld, bmu, blv, out);
}